// Round 7
// baseline (928.960 us; speedup 1.0000x reference)
//
#include <hip/hip_runtime.h>

// GAT (2-layer, PyG GATConv semantics) on MI355X — src-major aggregation.
// N=20000 nodes, E=100000 edges (+N self-loops), D=64, H=16 heads, C=64 ch/head.
constexpr int TD  = 64;      // input feature dim
constexpr int TH  = 16;      // heads
constexpr int TC  = 64;      // channels per head
constexpr int THC = TH * TC; // 1024
constexpr int MAXP = 128;    // max in-degree cached in LDS (overflow -> global path)

// ---------------- CSR/CSC build (once, shared by both layers) ----------------

__global__ void k_zero_int(int* p, int n) {
  int i = blockIdx.x * blockDim.x + threadIdx.x;
  if (i < n) p[i] = 0;
}

// count in-degree (by dst) and out-degree (by src) in one pass; self-loops e in [E,E+N)
__global__ void k_count2(const int* __restrict__ src, const int* __restrict__ dst,
                         int E, int N, int* __restrict__ degd, int* __restrict__ degs) {
  int e = blockIdx.x * blockDim.x + threadIdx.x;
  if (e >= E + N) return;
  int s, d;
  if (e < E) { s = src[e]; d = dst[e]; } else { s = d = e - E; }
  atomicAdd(&degd[d], 1);
  atomicAdd(&degs[s], 1);
}

// two independent single-block exclusive scans (block 0: dst-CSR, block 1: src-CSR)
__global__ void k_scan2(const int* __restrict__ degd, int N,
                        int* __restrict__ row_start, int* __restrict__ cursor,
                        const int* __restrict__ degs,
                        int* __restrict__ srow, int* __restrict__ scursor) {
  const int* dg = blockIdx.x ? degs : degd;
  int* rs = blockIdx.x ? srow : row_start;
  int* cu = blockIdx.x ? scursor : cursor;
  __shared__ int part[256];
  int t = threadIdx.x;
  int chunk = (N + 255) / 256;
  int lo = t * chunk, hi = min(lo + chunk, N);
  int s = 0;
  for (int i = lo; i < hi; ++i) s += dg[i];
  part[t] = s;
  __syncthreads();
  if (t == 0) {
    int run = 0;
    for (int i = 0; i < 256; ++i) { int v = part[i]; part[i] = run; run += v; }
    rs[N] = run;
  }
  __syncthreads();
  int run = part[t];
  for (int i = lo; i < hi; ++i) {
    rs[i] = run; cu[i] = run; run += dg[i];
  }
}

// dst-CSR scatter: position i holds edge eid[i] with source srcc[i]; inv[e] = i
__global__ void k_scatter_dst(const int* __restrict__ src, const int* __restrict__ dst,
                              int E, int N, int* __restrict__ cursor,
                              int* __restrict__ eid, int* __restrict__ srcc,
                              int* __restrict__ inv) {
  int e = blockIdx.x * blockDim.x + threadIdx.x;
  if (e >= E + N) return;
  int s, d;
  if (e < E) { s = src[e]; d = dst[e]; } else { s = d = e - E; }
  int pos = atomicAdd(&cursor[d], 1);
  eid[pos] = e; srcc[pos] = s; inv[e] = pos;
}

// src-CSR scatter: smap[j] = dst-CSR position of the j-th out-edge
__global__ void k_scatter_src(const int* __restrict__ src, int E, int N,
                              int* __restrict__ scursor, const int* __restrict__ inv,
                              int* __restrict__ smap) {
  int e = blockIdx.x * blockDim.x + threadIdx.x;
  if (e >= E + N) return;
  int s = (e < E) ? src[e] : (e - E);
  int j = atomicAdd(&scursor[s], 1);
  smap[j] = inv[e];
}

// ---------------- per-layer kernels ----------------

// xp = x[N,64] @ W[64,1024], 64x64 tiles. Linear grid of nrb*16 blocks with
// bijective XCD swizzle (m204) so one XCD runs all 16 heads of a row-block
// back-to-back: x-tile is fetched ~once into that XCD's L2 (FETCH 41->~8 MB).
// W (256 KB) is read straight from L2 with a 4-deep register prefetch — no W
// LDS tile, so LDS/block = 16 KB -> 8 blocks/CU (vs 5).
// Fused epilogue: al_s[n,h] = <xp[n,h,:], a_src[h,:]>, al_d likewise.
// x-tile stored k-major, XOR swizzle S(k)=k&28 -> conflict-free ds_read_b128.
__global__ __launch_bounds__(256) void k_matmul(const float* __restrict__ x,
                                                const float* __restrict__ W,
                                                const float* __restrict__ a_src,
                                                const float* __restrict__ a_dst,
                                                int N, int nrb, float* __restrict__ xp,
                                                float* __restrict__ al_s,
                                                float* __restrict__ al_d) {
  __shared__ float xs[64 * 64];  // k-major, swizzled
  int tid = threadIdx.x;
  // bijective XCD swizzle: dispatch slot -> logical block
  int nwg = nrb * 16;
  int wg = blockIdx.x;
  int q = nwg >> 3, rm = nwg & 7;
  int xcd = wg & 7, off = wg >> 3;
  int g = (xcd < rm ? xcd * (q + 1) : rm * (q + 1) + (xcd - rm) * q) + off;
  int h  = g & 15;               // head == column tile (c0 = h*64)
  int rb = g >> 4;
  int r0 = rb * 64;
  int c0 = h * 64;

  for (int idx = tid * 4; idx < 64 * 64; idx += 1024) {
    int r = idx >> 6, c = idx & 63;          // c multiple of 4
    float4 v = make_float4(0.f, 0.f, 0.f, 0.f);
    if (r0 + r < N) v = *(const float4*)&x[(size_t)(r0 + r) * TD + c];
    xs[(c + 0) * 64 + (r ^ ((c + 0) & 28))] = v.x;
    xs[(c + 1) * 64 + (r ^ ((c + 1) & 28))] = v.y;
    xs[(c + 2) * 64 + (r ^ ((c + 2) & 28))] = v.z;
    xs[(c + 3) * 64 + (r ^ ((c + 3) & 28))] = v.w;
  }
  __syncthreads();

  int ty = tid >> 4, tx = tid & 15;
  const float* Wc = W + c0 + tx * 4;         // this thread's 4 columns
  float acc[4][4] = {};
  float4 bn0 = *(const float4*)&Wc[0 * THC];
  float4 bn1 = *(const float4*)&Wc[1 * THC];
  float4 bn2 = *(const float4*)&Wc[2 * THC];
  float4 bn3 = *(const float4*)&Wc[3 * THC];
  for (int k4 = 0; k4 < 64; k4 += 4) {
    float4 bb[4] = {bn0, bn1, bn2, bn3};
    if (k4 < 60) {
      const float* Wp = Wc + (size_t)(k4 + 4) * THC;
      bn0 = *(const float4*)&Wp[0 * THC];
      bn1 = *(const float4*)&Wp[1 * THC];
      bn2 = *(const float4*)&Wp[2 * THC];
      bn3 = *(const float4*)&Wp[3 * THC];
    }
#pragma unroll
    for (int j = 0; j < 4; ++j) {
      int k = k4 + j;
      float4 b = bb[j];
      float4 a = *(const float4*)&xs[k * 64 + ((ty * 4) ^ (k & 28))];
      acc[0][0] += a.x * b.x; acc[0][1] += a.x * b.y; acc[0][2] += a.x * b.z; acc[0][3] += a.x * b.w;
      acc[1][0] += a.y * b.x; acc[1][1] += a.y * b.y; acc[1][2] += a.y * b.z; acc[1][3] += a.y * b.w;
      acc[2][0] += a.z * b.x; acc[2][1] += a.z * b.y; acc[2][2] += a.z * b.z; acc[2][3] += a.z * b.w;
      acc[3][0] += a.w * b.x; acc[3][1] += a.w * b.y; acc[3][2] += a.w * b.z; acc[3][3] += a.w * b.w;
    }
  }
  float4 asv = *(const float4*)&a_src[h * TC + tx * 4];
  float4 adv = *(const float4*)&a_dst[h * TC + tx * 4];
  for (int i = 0; i < 4; ++i) {
    int r = r0 + ty * 4 + i;
    float ps = acc[i][0] * asv.x + acc[i][1] * asv.y + acc[i][2] * asv.z + acc[i][3] * asv.w;
    float pd = acc[i][0] * adv.x + acc[i][1] * adv.y + acc[i][2] * adv.z + acc[i][3] * adv.w;
    for (int m = 8; m >= 1; m >>= 1) {
      ps += __shfl_xor(ps, m, 16);
      pd += __shfl_xor(pd, m, 16);
    }
    if (r < N) {
      *(float4*)&xp[(size_t)r * THC + c0 + tx * 4] =
          make_float4(acc[i][0], acc[i][1], acc[i][2], acc[i][3]);
      if (tx == 0) { al_s[r * TH + h] = ps; al_d[r * TH + h] = pd; }
    }
  }
}

// w_e[d,h] = sum_c We[d, h*64+c] * a_e[h,c]
__global__ void k_we(const float* __restrict__ We, const float* __restrict__ a_e,
                     float* __restrict__ w_e) {
  int t = blockIdx.x * blockDim.x + threadIdx.x;
  if (t >= TD * TH) return;
  int d = t >> 4, h = t & 15;
  float s = 0.f;
  for (int c = 0; c < TC; ++c) s += We[(size_t)d * THC + h * TC + c] * a_e[h * TC + c];
  w_e[d * TH + h] = s;
}

// ale[e,h] = <ea_row(e), w_e[:,h]> for REAL edges only (coalesced over e)
__global__ __launch_bounds__(256) void k_al_e(const float* __restrict__ ea,
                                              const float* __restrict__ w_e,
                                              int E, float* __restrict__ ale) {
  __shared__ float sea[16][64];
  __shared__ float swe[TD * TH];
  int tid = threadIdx.x;
  int e0 = blockIdx.x * 16;
  for (int i = tid; i < TD * TH; i += 256) swe[i] = w_e[i];
  {
    int idx = tid * 4;
    int le = idx >> 6, d = idx & 63;
    int e = e0 + le;
    float4 v = make_float4(0.f, 0.f, 0.f, 0.f);
    if (e < E) v = *(const float4*)&ea[(size_t)e * TD + d];
    *(float4*)&sea[le][d] = v;
  }
  __syncthreads();
  int le = tid >> 4, h = tid & 15;
  int e = e0 + le;
  if (e >= E) return;
  float s = 0.f;
  for (int dd = 0; dd < TD; ++dd) {
    int d = (dd + le * 8) & 63;              // rotate start: conflict-free LDS banks
    s += sea[le][d] * swe[d * TH + h];
  }
  ale[(size_t)e * TH + h] = s;
}

// per-dst block: self-loop ale mean (linearity) + alpha + segment softmax,
// writes normalized att[i][h] in dst-CSR position order. 256 thr = 16 pos-slots x 16 heads.
__global__ __launch_bounds__(256) void k_att(
    const float* __restrict__ al_s, const float* __restrict__ al_d,
    const float* __restrict__ ale, const int* __restrict__ row_start,
    const int* __restrict__ eid, const int* __restrict__ srcc,
    int E, float* __restrict__ att) {
  __shared__ float sal[MAXP][TH];            // 8 KB: alpha per cached position
  __shared__ float sred[16][TH + 1];
  __shared__ float sLale[TH], sM[TH], sDi[TH];
  __shared__ int sSelfP;
  int n = blockIdx.x, tid = threadIdx.x;
  int h = tid & 15, q = tid >> 4;
  int beg = row_start[n], end = row_start[n + 1], deg = end - beg;
  float ald = al_d[n * TH + h];

  if (tid == 0) sSelfP = -1;
  __syncthreads();

  // pass 1: gather al_s[src]+ald (+ale for real edges); accumulate ale-sum
  float asum = 0.f;
  for (int p = q; p < deg; p += 16) {
    int i = beg + p;
    int e = eid[i], s = srcc[i];
    float av = 0.f;
    if (e < E) { av = ale[(size_t)e * TH + h]; asum += av; }
    else if (h == 0) sSelfP = p;             // exactly one self-loop per node
    if (p < MAXP) sal[p][h] = al_s[s * TH + h] + ald + av;
  }
  sred[q][h] = asum;
  __syncthreads();
  if (q == 0) {
    float t = 0.f;
    for (int qq = 0; qq < 16; ++qq) t += sred[qq][h];
    sLale[h] = t / (float)max(deg - 1, 1);   // mean ale of real in-edges
  }
  __syncthreads();

  int selfp = sSelfP;
  auto full_a = [&](int i) -> float {        // overflow path (deg > MAXP), exact math
    int e = eid[i], s = srcc[i];
    float av = (e < E) ? ale[(size_t)e * TH + h] : sLale[h];
    float a = al_s[s * TH + h] + ald + av;
    return (a > 0.f) ? a : 0.2f * a;
  };

  // pass 2: finalize alpha (add lale to self, leaky_relu), partial max
  float mloc = -1e30f;
  for (int p = q; p < deg; p += 16) {
    float a;
    if (p < MAXP) {
      a = sal[p][h];
      if (p == selfp) a += sLale[h];
      a = (a > 0.f) ? a : 0.2f * a;
      sal[p][h] = a;
    } else a = full_a(beg + p);
    mloc = fmaxf(mloc, a);
  }
  sred[q][h] = mloc;
  __syncthreads();
  if (q == 0) {
    float m = -1e30f;
    for (int qq = 0; qq < 16; ++qq) m = fmaxf(m, sred[qq][h]);
    sM[h] = m;
  }
  __syncthreads();

  // pass 3: partial denominator
  float dloc = 0.f;
  for (int p = q; p < deg; p += 16) {
    float a = (p < MAXP) ? sal[p][h] : full_a(beg + p);
    dloc += expf(a - sM[h]);
  }
  sred[q][h] = dloc;
  __syncthreads();
  if (q == 0) {
    float d = 0.f;
    for (int qq = 0; qq < 16; ++qq) d += sred[qq][h];
    sDi[h] = 1.f / (d + 1e-16f);
  }
  __syncthreads();

  // pass 4: write normalized attention (coalesced 64B chunks per position)
  for (int p = q; p < deg; p += 16) {
    float a = (p < MAXP) ? sal[p][h] : full_a(beg + p);
    att[(size_t)(beg + p) * TH + h] = expf(a - sM[h]) * sDi[h];
  }
}

// src-major: stage xp[s] once in LDS; per out-edge fold heads:
// z[i][c] = sum_h att[i,h] * xp[s,h,c], written in dst-CSR position order.
// 16 slots x 16 lanes, float4 per lane: 256B z-row per edge, 4x fewer instrs.
__global__ __launch_bounds__(256) void k_csc_z(const float* __restrict__ xp,
                                               const float* __restrict__ att,
                                               const int* __restrict__ srow,
                                               const int* __restrict__ smap,
                                               float* __restrict__ z) {
  __shared__ float sx[THC];                  // 4 KB
  int s = blockIdx.x, tid = threadIdx.x;
  int beg = srow[s], end = srow[s + 1];
  *(float4*)&sx[tid * 4] = *(const float4*)&xp[(size_t)s * THC + tid * 4];
  __syncthreads();
  int slot = tid >> 4, c4 = (tid & 15) * 4;
  for (int j = beg + slot; j < end; j += 16) {
    int i = smap[j];
    const float* ar = &att[(size_t)i * TH];
    float4 a0 = *(const float4*)&ar[0];
    float4 a1 = *(const float4*)&ar[4];
    float4 a2 = *(const float4*)&ar[8];
    float4 a3 = *(const float4*)&ar[12];
    float aw[16] = {a0.x, a0.y, a0.z, a0.w, a1.x, a1.y, a1.z, a1.w,
                    a2.x, a2.y, a2.z, a2.w, a3.x, a3.y, a3.z, a3.w};
    float4 acc = make_float4(0.f, 0.f, 0.f, 0.f);
#pragma unroll
    for (int hh = 0; hh < TH; ++hh) {
      float4 v = *(const float4*)&sx[hh * 64 + c4];
      acc.x += aw[hh] * v.x; acc.y += aw[hh] * v.y;
      acc.z += aw[hh] * v.z; acc.w += aw[hh] * v.w;
    }
    *(float4*)&z[(size_t)i * 64 + c4] = acc;
  }
}

// per-dst: sum contiguous z segment, head-mean + bias + relu.
// 16 nodes per block, 16 lanes x float4 per node.
__global__ __launch_bounds__(256) void k_sum_z(const float* __restrict__ z,
                                               const int* __restrict__ row_start,
                                               const float* __restrict__ bias, int N,
                                               float* __restrict__ out) {
  int tid = threadIdx.x;
  int n = blockIdx.x * 16 + (tid >> 4);
  int c4 = (tid & 15) * 4;
  if (n >= N) return;
  int beg = row_start[n], end = row_start[n + 1];
  float4 acc = make_float4(0.f, 0.f, 0.f, 0.f);
  for (int i = beg; i < end; ++i) {
    float4 v = *(const float4*)&z[(size_t)i * 64 + c4];
    acc.x += v.x; acc.y += v.y; acc.z += v.z; acc.w += v.w;
  }
  float4 b = *(const float4*)&bias[c4];
  float4 o;
  o.x = fmaxf(acc.x * (1.0f / TH) + b.x, 0.f);
  o.y = fmaxf(acc.y * (1.0f / TH) + b.y, 0.f);
  o.z = fmaxf(acc.z * (1.0f / TH) + b.z, 0.f);
  o.w = fmaxf(acc.w * (1.0f / TH) + b.w, 0.f);
  *(float4*)&out[(size_t)n * 64 + c4] = o;
}

// ---------------- launch ----------------

extern "C" void kernel_launch(void* const* d_in, const int* in_sizes, int n_in,
                              void* d_out, int out_size, void* d_ws, size_t ws_size,
                              hipStream_t stream) {
  const float* x   = (const float*)d_in[0];
  const int*   ei  = (const int*)d_in[1];
  const float* ea  = (const float*)d_in[2];
  const float* W1  = (const float*)d_in[3];
  const float* as1 = (const float*)d_in[4];
  const float* ad1 = (const float*)d_in[5];
  const float* We1 = (const float*)d_in[6];
  const float* ae1 = (const float*)d_in[7];
  const float* b1  = (const float*)d_in[8];
  const float* W2  = (const float*)d_in[9];
  const float* as2 = (const float*)d_in[10];
  const float* ad2 = (const float*)d_in[11];
  const float* We2 = (const float*)d_in[12];
  const float* ae2 = (const float*)d_in[13];
  const float* b2  = (const float*)d_in[14];

  const int N  = in_sizes[0] / TD;   // 20000
  const int E  = in_sizes[1] / 2;    // 100000
  const int EN = E + N;              // 120000 (with self-loops)
  const int* srcA = ei;
  const int* dstA = ei + E;

  char* w = (char*)d_ws;
  auto alloc = [&](size_t bytes) {
    char* p = w;
    w += (bytes + 255) & ~(size_t)255;
    return p;
  };
  int*   deg2      = (int*)alloc((size_t)2 * N * 4);      // degd | degs
  int*   degd      = deg2;
  int*   degs      = deg2 + N;
  int*   row_start = (int*)alloc((size_t)(N + 1) * 4);
  int*   srow      = (int*)alloc((size_t)(N + 1) * 4);
  int*   cursor    = (int*)alloc((size_t)N * 4);
  int*   scursor   = (int*)alloc((size_t)N * 4);
  int*   eid       = (int*)alloc((size_t)EN * 4);
  int*   srcc      = (int*)alloc((size_t)EN * 4);
  int*   inv       = (int*)alloc((size_t)EN * 4);
  int*   smap      = (int*)alloc((size_t)EN * 4);
  float* xp        = (float*)alloc((size_t)N * THC * 4);  // 82 MB
  float* al_s      = (float*)alloc((size_t)N * TH * 4);
  float* al_d      = (float*)alloc((size_t)N * TH * 4);
  float* ale       = (float*)alloc((size_t)E * TH * 4);   // 6.4 MB, real edges only
  float* att       = (float*)alloc((size_t)EN * TH * 4);  // 7.7 MB
  float* z         = (float*)alloc((size_t)EN * TC * 4);  // 30.7 MB
  float* w_e       = (float*)alloc((size_t)TD * TH * 4);
  float* hbuf      = (float*)ale;  // overlay: ale dead after k_att; layer-2 k_al_e
                                   // rewrites ale only after matmul2 consumed hbuf

  // CSR (by dst) + CSC (by src) build, shared by both layers
  k_zero_int<<<(2 * N + 255) / 256, 256, 0, stream>>>(deg2, 2 * N);
  k_count2<<<(EN + 255) / 256, 256, 0, stream>>>(srcA, dstA, E, N, degd, degs);
  k_scan2<<<2, 256, 0, stream>>>(degd, N, row_start, cursor, degs, srow, scursor);
  k_scatter_dst<<<(EN + 255) / 256, 256, 0, stream>>>(srcA, dstA, E, N, cursor, eid, srcc, inv);
  k_scatter_src<<<(EN + 255) / 256, 256, 0, stream>>>(srcA, E, N, scursor, inv, smap);

  const int nrb = (N + 63) / 64;     // 313 row blocks
  const int mmgrid = nrb * 16;       // 5008 blocks, linear (XCD-swizzled inside)

  // layer 1
  k_matmul<<<mmgrid, 256, 0, stream>>>(x, W1, as1, ad1, N, nrb, xp, al_s, al_d);
  k_we<<<4, 256, 0, stream>>>(We1, ae1, w_e);
  k_al_e<<<(E + 15) / 16, 256, 0, stream>>>(ea, w_e, E, ale);
  k_att<<<N, 256, 0, stream>>>(al_s, al_d, ale, row_start, eid, srcc, E, att);
  k_csc_z<<<N, 256, 0, stream>>>(xp, att, srow, smap, z);
  k_sum_z<<<(N + 15) / 16, 256, 0, stream>>>(z, row_start, b1, N, hbuf);

  // layer 2
  k_matmul<<<mmgrid, 256, 0, stream>>>(hbuf, W2, as2, ad2, N, nrb, xp, al_s, al_d);
  k_we<<<4, 256, 0, stream>>>(We2, ae2, w_e);
  k_al_e<<<(E + 15) / 16, 256, 0, stream>>>(ea, w_e, E, ale);
  k_att<<<N, 256, 0, stream>>>(al_s, al_d, ale, row_start, eid, srcc, E, att);
  k_csc_z<<<N, 256, 0, stream>>>(xp, att, srow, smap, z);
  k_sum_z<<<(N + 15) / 16, 256, 0, stream>>>(z, row_start, b2, N, (float*)d_out);
}

// Round 8
// 339.269 us; speedup vs baseline: 2.7381x; 2.7381x over previous
//
#include <hip/hip_runtime.h>

// GAT (2-layer, PyG GATConv semantics) on MI355X — src-major aggregation.
// N=20000 nodes, E=100000 edges (+N self-loops), D=64, H=16 heads, C=64 ch/head.
constexpr int TD  = 64;      // input feature dim
constexpr int TH  = 16;      // heads
constexpr int TC  = 64;      // channels per head
constexpr int THC = TH * TC; // 1024
constexpr int MAXP = 128;    // max in-degree cached in LDS (overflow -> global path)

// ---------------- CSR/CSC build (once, shared by both layers) ----------------

__global__ void k_zero_int(int* p, int n) {
  int i = blockIdx.x * blockDim.x + threadIdx.x;
  if (i < n) p[i] = 0;
}

// count in-degree (by dst) and out-degree (by src) in one pass; self-loops e in [E,E+N)
__global__ void k_count2(const int* __restrict__ src, const int* __restrict__ dst,
                         int E, int N, int* __restrict__ degd, int* __restrict__ degs) {
  int e = blockIdx.x * blockDim.x + threadIdx.x;
  if (e >= E + N) return;
  int s, d;
  if (e < E) { s = src[e]; d = dst[e]; } else { s = d = e - E; }
  atomicAdd(&degd[d], 1);
  atomicAdd(&degs[s], 1);
}

// two independent single-block exclusive scans (block 0: dst-CSR, block 1: src-CSR)
__global__ void k_scan2(const int* __restrict__ degd, int N,
                        int* __restrict__ row_start, int* __restrict__ cursor,
                        const int* __restrict__ degs,
                        int* __restrict__ srow, int* __restrict__ scursor) {
  const int* dg = blockIdx.x ? degs : degd;
  int* rs = blockIdx.x ? srow : row_start;
  int* cu = blockIdx.x ? scursor : cursor;
  __shared__ int part[256];
  int t = threadIdx.x;
  int chunk = (N + 255) / 256;
  int lo = t * chunk, hi = min(lo + chunk, N);
  int s = 0;
  for (int i = lo; i < hi; ++i) s += dg[i];
  part[t] = s;
  __syncthreads();
  if (t == 0) {
    int run = 0;
    for (int i = 0; i < 256; ++i) { int v = part[i]; part[i] = run; run += v; }
    rs[N] = run;
  }
  __syncthreads();
  int run = part[t];
  for (int i = lo; i < hi; ++i) {
    rs[i] = run; cu[i] = run; run += dg[i];
  }
}

// dst-CSR scatter: position i holds edge eid[i] with source srcc[i]; inv[e] = i
__global__ void k_scatter_dst(const int* __restrict__ src, const int* __restrict__ dst,
                              int E, int N, int* __restrict__ cursor,
                              int* __restrict__ eid, int* __restrict__ srcc,
                              int* __restrict__ inv) {
  int e = blockIdx.x * blockDim.x + threadIdx.x;
  if (e >= E + N) return;
  int s, d;
  if (e < E) { s = src[e]; d = dst[e]; } else { s = d = e - E; }
  int pos = atomicAdd(&cursor[d], 1);
  eid[pos] = e; srcc[pos] = s; inv[e] = pos;
}

// src-CSR scatter: smap[j] = dst-CSR position of the j-th out-edge
__global__ void k_scatter_src(const int* __restrict__ src, int E, int N,
                              int* __restrict__ scursor, const int* __restrict__ inv,
                              int* __restrict__ smap) {
  int e = blockIdx.x * blockDim.x + threadIdx.x;
  if (e >= E + N) return;
  int s = (e < E) ? src[e] : (e - E);
  int j = atomicAdd(&scursor[s], 1);
  smap[j] = inv[e];
}

// ---------------- per-layer kernels ----------------

// xp = x[N,64] @ W[64,1024], 64x64 tiles. Linear grid of nrb*16 blocks with
// bijective XCD swizzle (m204): one XCD runs all 16 heads of a row-block
// back-to-back -> x-tile L2-resident per XCD (FETCH 41->27 MB, measured R7).
// W tile staged in LDS (ws[64][64], 16 KB): R7's register-prefetch variant
// spilled (VGPR 256, +474 MB scratch writes) — keep W in LDS. 44 VGPR.
// Fused epilogue: al_s[n,h] = <xp[n,h,:], a_src[h,:]>, al_d likewise.
// x-tile stored k-major, XOR swizzle S(k)=k&28 -> conflict-free ds_read_b128.
__global__ __launch_bounds__(256) void k_matmul(const float* __restrict__ x,
                                                const float* __restrict__ W,
                                                const float* __restrict__ a_src,
                                                const float* __restrict__ a_dst,
                                                int N, int nrb, float* __restrict__ xp,
                                                float* __restrict__ al_s,
                                                float* __restrict__ al_d) {
  __shared__ float xs[64 * 64];  // k-major, swizzled
  __shared__ float ws[64][64];
  int tid = threadIdx.x;
  // bijective XCD swizzle: dispatch slot -> logical block
  int nwg = nrb * 16;
  int wg = blockIdx.x;
  int q = nwg >> 3, rm = nwg & 7;
  int xcd = wg & 7, off = wg >> 3;
  int g = (xcd < rm ? xcd * (q + 1) : rm * (q + 1) + (xcd - rm) * q) + off;
  int h  = g & 15;               // head == column tile (c0 = h*64)
  int rb = g >> 4;
  int r0 = rb * 64;
  int c0 = h * 64;

  for (int idx = tid * 4; idx < 64 * 64; idx += 1024) {
    int r = idx >> 6, c = idx & 63;          // c multiple of 4
    float4 v = make_float4(0.f, 0.f, 0.f, 0.f);
    if (r0 + r < N) v = *(const float4*)&x[(size_t)(r0 + r) * TD + c];
    xs[(c + 0) * 64 + (r ^ ((c + 0) & 28))] = v.x;
    xs[(c + 1) * 64 + (r ^ ((c + 1) & 28))] = v.y;
    xs[(c + 2) * 64 + (r ^ ((c + 2) & 28))] = v.z;
    xs[(c + 3) * 64 + (r ^ ((c + 3) & 28))] = v.w;
    *(float4*)&ws[r][c] = *(const float4*)&W[(size_t)r * THC + c0 + c];  // r == k
  }
  __syncthreads();

  int ty = tid >> 4, tx = tid & 15;
  float acc[4][4] = {};
  for (int k = 0; k < 64; ++k) {
    float4 a = *(const float4*)&xs[k * 64 + ((ty * 4) ^ (k & 28))];
    float4 b = *(const float4*)&ws[k][tx * 4];
    acc[0][0] += a.x * b.x; acc[0][1] += a.x * b.y; acc[0][2] += a.x * b.z; acc[0][3] += a.x * b.w;
    acc[1][0] += a.y * b.x; acc[1][1] += a.y * b.y; acc[1][2] += a.y * b.z; acc[1][3] += a.y * b.w;
    acc[2][0] += a.z * b.x; acc[2][1] += a.z * b.y; acc[2][2] += a.z * b.z; acc[2][3] += a.z * b.w;
    acc[3][0] += a.w * b.x; acc[3][1] += a.w * b.y; acc[3][2] += a.w * b.z; acc[3][3] += a.w * b.w;
  }
  float4 asv = *(const float4*)&a_src[h * TC + tx * 4];
  float4 adv = *(const float4*)&a_dst[h * TC + tx * 4];
  for (int i = 0; i < 4; ++i) {
    int r = r0 + ty * 4 + i;
    float ps = acc[i][0] * asv.x + acc[i][1] * asv.y + acc[i][2] * asv.z + acc[i][3] * asv.w;
    float pd = acc[i][0] * adv.x + acc[i][1] * adv.y + acc[i][2] * adv.z + acc[i][3] * adv.w;
    for (int m = 8; m >= 1; m >>= 1) {
      ps += __shfl_xor(ps, m, 16);
      pd += __shfl_xor(pd, m, 16);
    }
    if (r < N) {
      *(float4*)&xp[(size_t)r * THC + c0 + tx * 4] =
          make_float4(acc[i][0], acc[i][1], acc[i][2], acc[i][3]);
      if (tx == 0) { al_s[r * TH + h] = ps; al_d[r * TH + h] = pd; }
    }
  }
}

// w_e[d,h] = sum_c We[d, h*64+c] * a_e[h,c]
__global__ void k_we(const float* __restrict__ We, const float* __restrict__ a_e,
                     float* __restrict__ w_e) {
  int t = blockIdx.x * blockDim.x + threadIdx.x;
  if (t >= TD * TH) return;
  int d = t >> 4, h = t & 15;
  float s = 0.f;
  for (int c = 0; c < TC; ++c) s += We[(size_t)d * THC + h * TC + c] * a_e[h * TC + c];
  w_e[d * TH + h] = s;
}

// ale[e,h] = <ea_row(e), w_e[:,h]> for REAL edges only (coalesced over e)
__global__ __launch_bounds__(256) void k_al_e(const float* __restrict__ ea,
                                              const float* __restrict__ w_e,
                                              int E, float* __restrict__ ale) {
  __shared__ float sea[16][64];
  __shared__ float swe[TD * TH];
  int tid = threadIdx.x;
  int e0 = blockIdx.x * 16;
  for (int i = tid; i < TD * TH; i += 256) swe[i] = w_e[i];
  {
    int idx = tid * 4;
    int le = idx >> 6, d = idx & 63;
    int e = e0 + le;
    float4 v = make_float4(0.f, 0.f, 0.f, 0.f);
    if (e < E) v = *(const float4*)&ea[(size_t)e * TD + d];
    *(float4*)&sea[le][d] = v;
  }
  __syncthreads();
  int le = tid >> 4, h = tid & 15;
  int e = e0 + le;
  if (e >= E) return;
  float s = 0.f;
  for (int dd = 0; dd < TD; ++dd) {
    int d = (dd + le * 8) & 63;              // rotate start: conflict-free LDS banks
    s += sea[le][d] * swe[d * TH + h];
  }
  ale[(size_t)e * TH + h] = s;
}

// per-dst block: self-loop ale mean (linearity) + alpha + segment softmax,
// writes normalized att[i][h] in dst-CSR position order. 256 thr = 16 pos-slots x 16 heads.
__global__ __launch_bounds__(256) void k_att(
    const float* __restrict__ al_s, const float* __restrict__ al_d,
    const float* __restrict__ ale, const int* __restrict__ row_start,
    const int* __restrict__ eid, const int* __restrict__ srcc,
    int E, float* __restrict__ att) {
  __shared__ float sal[MAXP][TH];            // 8 KB: alpha per cached position
  __shared__ float sred[16][TH + 1];
  __shared__ float sLale[TH], sM[TH], sDi[TH];
  __shared__ int sSelfP;
  int n = blockIdx.x, tid = threadIdx.x;
  int h = tid & 15, q = tid >> 4;
  int beg = row_start[n], end = row_start[n + 1], deg = end - beg;
  float ald = al_d[n * TH + h];

  if (tid == 0) sSelfP = -1;
  __syncthreads();

  // pass 1: gather al_s[src]+ald (+ale for real edges); accumulate ale-sum
  float asum = 0.f;
  for (int p = q; p < deg; p += 16) {
    int i = beg + p;
    int e = eid[i], s = srcc[i];
    float av = 0.f;
    if (e < E) { av = ale[(size_t)e * TH + h]; asum += av; }
    else if (h == 0) sSelfP = p;             // exactly one self-loop per node
    if (p < MAXP) sal[p][h] = al_s[s * TH + h] + ald + av;
  }
  sred[q][h] = asum;
  __syncthreads();
  if (q == 0) {
    float t = 0.f;
    for (int qq = 0; qq < 16; ++qq) t += sred[qq][h];
    sLale[h] = t / (float)max(deg - 1, 1);   // mean ale of real in-edges
  }
  __syncthreads();

  int selfp = sSelfP;
  auto full_a = [&](int i) -> float {        // overflow path (deg > MAXP), exact math
    int e = eid[i], s = srcc[i];
    float av = (e < E) ? ale[(size_t)e * TH + h] : sLale[h];
    float a = al_s[s * TH + h] + ald + av;
    return (a > 0.f) ? a : 0.2f * a;
  };

  // pass 2: finalize alpha (add lale to self, leaky_relu), partial max
  float mloc = -1e30f;
  for (int p = q; p < deg; p += 16) {
    float a;
    if (p < MAXP) {
      a = sal[p][h];
      if (p == selfp) a += sLale[h];
      a = (a > 0.f) ? a : 0.2f * a;
      sal[p][h] = a;
    } else a = full_a(beg + p);
    mloc = fmaxf(mloc, a);
  }
  sred[q][h] = mloc;
  __syncthreads();
  if (q == 0) {
    float m = -1e30f;
    for (int qq = 0; qq < 16; ++qq) m = fmaxf(m, sred[qq][h]);
    sM[h] = m;
  }
  __syncthreads();

  // pass 3: partial denominator
  float dloc = 0.f;
  for (int p = q; p < deg; p += 16) {
    float a = (p < MAXP) ? sal[p][h] : full_a(beg + p);
    dloc += expf(a - sM[h]);
  }
  sred[q][h] = dloc;
  __syncthreads();
  if (q == 0) {
    float d = 0.f;
    for (int qq = 0; qq < 16; ++qq) d += sred[qq][h];
    sDi[h] = 1.f / (d + 1e-16f);
  }
  __syncthreads();

  // pass 4: write normalized attention (coalesced 64B chunks per position)
  for (int p = q; p < deg; p += 16) {
    float a = (p < MAXP) ? sal[p][h] : full_a(beg + p);
    att[(size_t)(beg + p) * TH + h] = expf(a - sM[h]) * sDi[h];
  }
}

// src-major: stage xp[s] once in LDS; per out-edge fold heads:
// z[i][c] = sum_h att[i,h] * xp[s,h,c], written in dst-CSR position order.
// 16 slots x 16 lanes, float4 per lane: 256B z-row per edge.
__global__ __launch_bounds__(256) void k_csc_z(const float* __restrict__ xp,
                                               const float* __restrict__ att,
                                               const int* __restrict__ srow,
                                               const int* __restrict__ smap,
                                               float* __restrict__ z) {
  __shared__ float sx[THC];                  // 4 KB
  int s = blockIdx.x, tid = threadIdx.x;
  int beg = srow[s], end = srow[s + 1];
  *(float4*)&sx[tid * 4] = *(const float4*)&xp[(size_t)s * THC + tid * 4];
  __syncthreads();
  int slot = tid >> 4, c4 = (tid & 15) * 4;
  for (int j = beg + slot; j < end; j += 16) {
    int i = smap[j];
    const float* ar = &att[(size_t)i * TH];
    float4 a0 = *(const float4*)&ar[0];
    float4 a1 = *(const float4*)&ar[4];
    float4 a2 = *(const float4*)&ar[8];
    float4 a3 = *(const float4*)&ar[12];
    float aw[16] = {a0.x, a0.y, a0.z, a0.w, a1.x, a1.y, a1.z, a1.w,
                    a2.x, a2.y, a2.z, a2.w, a3.x, a3.y, a3.z, a3.w};
    float4 acc = make_float4(0.f, 0.f, 0.f, 0.f);
#pragma unroll
    for (int hh = 0; hh < TH; ++hh) {
      float4 v = *(const float4*)&sx[hh * 64 + c4];
      acc.x += aw[hh] * v.x; acc.y += aw[hh] * v.y;
      acc.z += aw[hh] * v.z; acc.w += aw[hh] * v.w;
    }
    *(float4*)&z[(size_t)i * 64 + c4] = acc;
  }
}

// per-dst: sum contiguous z segment, head-mean + bias + relu.
// 16 nodes per block, 16 lanes x float4 per node.
__global__ __launch_bounds__(256) void k_sum_z(const float* __restrict__ z,
                                               const int* __restrict__ row_start,
                                               const float* __restrict__ bias, int N,
                                               float* __restrict__ out) {
  int tid = threadIdx.x;
  int n = blockIdx.x * 16 + (tid >> 4);
  int c4 = (tid & 15) * 4;
  if (n >= N) return;
  int beg = row_start[n], end = row_start[n + 1];
  float4 acc = make_float4(0.f, 0.f, 0.f, 0.f);
  for (int i = beg; i < end; ++i) {
    float4 v = *(const float4*)&z[(size_t)i * 64 + c4];
    acc.x += v.x; acc.y += v.y; acc.z += v.z; acc.w += v.w;
  }
  float4 b = *(const float4*)&bias[c4];
  float4 o;
  o.x = fmaxf(acc.x * (1.0f / TH) + b.x, 0.f);
  o.y = fmaxf(acc.y * (1.0f / TH) + b.y, 0.f);
  o.z = fmaxf(acc.z * (1.0f / TH) + b.z, 0.f);
  o.w = fmaxf(acc.w * (1.0f / TH) + b.w, 0.f);
  *(float4*)&out[(size_t)n * 64 + c4] = o;
}

// ---------------- launch ----------------

extern "C" void kernel_launch(void* const* d_in, const int* in_sizes, int n_in,
                              void* d_out, int out_size, void* d_ws, size_t ws_size,
                              hipStream_t stream) {
  const float* x   = (const float*)d_in[0];
  const int*   ei  = (const int*)d_in[1];
  const float* ea  = (const float*)d_in[2];
  const float* W1  = (const float*)d_in[3];
  const float* as1 = (const float*)d_in[4];
  const float* ad1 = (const float*)d_in[5];
  const float* We1 = (const float*)d_in[6];
  const float* ae1 = (const float*)d_in[7];
  const float* b1  = (const float*)d_in[8];
  const float* W2  = (const float*)d_in[9];
  const float* as2 = (const float*)d_in[10];
  const float* ad2 = (const float*)d_in[11];
  const float* We2 = (const float*)d_in[12];
  const float* ae2 = (const float*)d_in[13];
  const float* b2  = (const float*)d_in[14];

  const int N  = in_sizes[0] / TD;   // 20000
  const int E  = in_sizes[1] / 2;    // 100000
  const int EN = E + N;              // 120000 (with self-loops)
  const int* srcA = ei;
  const int* dstA = ei + E;

  char* w = (char*)d_ws;
  auto alloc = [&](size_t bytes) {
    char* p = w;
    w += (bytes + 255) & ~(size_t)255;
    return p;
  };
  int*   deg2      = (int*)alloc((size_t)2 * N * 4);      // degd | degs
  int*   degd      = deg2;
  int*   degs      = deg2 + N;
  int*   row_start = (int*)alloc((size_t)(N + 1) * 4);
  int*   srow      = (int*)alloc((size_t)(N + 1) * 4);
  int*   cursor    = (int*)alloc((size_t)N * 4);
  int*   scursor   = (int*)alloc((size_t)N * 4);
  int*   eid       = (int*)alloc((size_t)EN * 4);
  int*   srcc      = (int*)alloc((size_t)EN * 4);
  int*   inv       = (int*)alloc((size_t)EN * 4);
  int*   smap      = (int*)alloc((size_t)EN * 4);
  float* xp        = (float*)alloc((size_t)N * THC * 4);  // 82 MB
  float* al_s      = (float*)alloc((size_t)N * TH * 4);
  float* al_d      = (float*)alloc((size_t)N * TH * 4);
  float* ale       = (float*)alloc((size_t)E * TH * 4);   // 6.4 MB, real edges only
  float* att       = (float*)alloc((size_t)EN * TH * 4);  // 7.7 MB
  float* z         = (float*)alloc((size_t)EN * TC * 4);  // 30.7 MB
  float* w_e       = (float*)alloc((size_t)TD * TH * 4);
  float* hbuf      = (float*)ale;  // overlay: ale dead after k_att; layer-2 k_al_e
                                   // rewrites ale only after matmul2 consumed hbuf

  // CSR (by dst) + CSC (by src) build, shared by both layers
  k_zero_int<<<(2 * N + 255) / 256, 256, 0, stream>>>(deg2, 2 * N);
  k_count2<<<(EN + 255) / 256, 256, 0, stream>>>(srcA, dstA, E, N, degd, degs);
  k_scan2<<<2, 256, 0, stream>>>(degd, N, row_start, cursor, degs, srow, scursor);
  k_scatter_dst<<<(EN + 255) / 256, 256, 0, stream>>>(srcA, dstA, E, N, cursor, eid, srcc, inv);
  k_scatter_src<<<(EN + 255) / 256, 256, 0, stream>>>(srcA, E, N, scursor, inv, smap);

  const int nrb = (N + 63) / 64;     // 313 row blocks
  const int mmgrid = nrb * 16;       // 5008 blocks, linear (XCD-swizzled inside)

  // layer 1
  k_matmul<<<mmgrid, 256, 0, stream>>>(x, W1, as1, ad1, N, nrb, xp, al_s, al_d);
  k_we<<<4, 256, 0, stream>>>(We1, ae1, w_e);
  k_al_e<<<(E + 15) / 16, 256, 0, stream>>>(ea, w_e, E, ale);
  k_att<<<N, 256, 0, stream>>>(al_s, al_d, ale, row_start, eid, srcc, E, att);
  k_csc_z<<<N, 256, 0, stream>>>(xp, att, srow, smap, z);
  k_sum_z<<<(N + 15) / 16, 256, 0, stream>>>(z, row_start, b1, N, hbuf);

  // layer 2
  k_matmul<<<mmgrid, 256, 0, stream>>>(hbuf, W2, as2, ad2, N, nrb, xp, al_s, al_d);
  k_we<<<4, 256, 0, stream>>>(We2, ae2, w_e);
  k_al_e<<<(E + 15) / 16, 256, 0, stream>>>(ea, w_e, E, ale);
  k_att<<<N, 256, 0, stream>>>(al_s, al_d, ale, row_start, eid, srcc, E, att);
  k_csc_z<<<N, 256, 0, stream>>>(xp, att, srow, smap, z);
  k_sum_z<<<(N + 15) / 16, 256, 0, stream>>>(z, row_start, b2, N, (float*)d_out);
}

// Round 9
// 309.854 us; speedup vs baseline: 2.9981x; 1.0949x over previous
//
#include <hip/hip_runtime.h>

// GAT (2-layer, PyG GATConv semantics) on MI355X — src-major aggregation.
// N=20000 nodes, E=100000 edges (+N self-loops), D=64, H=16 heads, C=64 ch/head.
constexpr int TD  = 64;      // input feature dim
constexpr int TH  = 16;      // heads
constexpr int TC  = 64;      // channels per head
constexpr int THC = TH * TC; // 1024

// ---------------- CSR/CSC build (once, shared by both layers) ----------------

// count in-degree (by dst) and out-degree (by src) in one pass; self-loops e in [E,E+N)
__global__ void k_count2(const int* __restrict__ src, const int* __restrict__ dst,
                         int E, int N, int* __restrict__ degd, int* __restrict__ degs) {
  int e = blockIdx.x * blockDim.x + threadIdx.x;
  if (e >= E + N) return;
  int s, d;
  if (e < E) { s = src[e]; d = dst[e]; } else { s = d = e - E; }
  atomicAdd(&degd[d], 1);
  atomicAdd(&degs[s], 1);
}

// two independent single-block exclusive scans (block 0: dst-CSR, block 1: src-CSR)
__global__ void k_scan2(const int* __restrict__ degd, int N,
                        int* __restrict__ row_start, int* __restrict__ cursor,
                        const int* __restrict__ degs,
                        int* __restrict__ srow, int* __restrict__ scursor) {
  const int* dg = blockIdx.x ? degs : degd;
  int* rs = blockIdx.x ? srow : row_start;
  int* cu = blockIdx.x ? scursor : cursor;
  __shared__ int part[256];
  int t = threadIdx.x;
  int chunk = (N + 255) / 256;
  int lo = t * chunk, hi = min(lo + chunk, N);
  int s = 0;
  for (int i = lo; i < hi; ++i) s += dg[i];
  part[t] = s;
  __syncthreads();
  if (t == 0) {
    int run = 0;
    for (int i = 0; i < 256; ++i) { int v = part[i]; part[i] = run; run += v; }
    rs[N] = run;
  }
  __syncthreads();
  int run = part[t];
  for (int i = lo; i < hi; ++i) {
    rs[i] = run; cu[i] = run; run += dg[i];
  }
}

// dst-CSR scatter: position i holds edge eid[i] with source srcc[i]; inv[e] = i
__global__ void k_scatter_dst(const int* __restrict__ src, const int* __restrict__ dst,
                              int E, int N, int* __restrict__ cursor,
                              int* __restrict__ eid, int* __restrict__ srcc,
                              int* __restrict__ inv) {
  int e = blockIdx.x * blockDim.x + threadIdx.x;
  if (e >= E + N) return;
  int s, d;
  if (e < E) { s = src[e]; d = dst[e]; } else { s = d = e - E; }
  int pos = atomicAdd(&cursor[d], 1);
  eid[pos] = e; srcc[pos] = s; inv[e] = pos;
}

// src-CSR scatter: smap[j] = dst-CSR position of the j-th out-edge
__global__ void k_scatter_src(const int* __restrict__ src, int E, int N,
                              int* __restrict__ scursor, const int* __restrict__ inv,
                              int* __restrict__ smap) {
  int e = blockIdx.x * blockDim.x + threadIdx.x;
  if (e >= E + N) return;
  int s = (e < E) ? src[e] : (e - E);
  int j = atomicAdd(&scursor[s], 1);
  smap[j] = inv[e];
}

// ---------------- per-layer kernels ----------------

// xp = x[N,64] @ W[64,1024], 64 rows x 2 heads (128 cols) per block.
// Linear grid nrb*8 with bijective XCD swizzle (m204): FETCH stays L2-resident
// (measured 3.6 MB, R8). W tiles in LDS (R7 lesson: register-prefetch spilled).
// 2 heads/block: halves x-staging, LDS-reads/FMA 0.125->0.094, acc=32 regs (safe).
// Fused epilogue: al_s[n,h] = <xp[n,h,:], a_src[h,:]>, al_d likewise.
// x-tile k-major, XOR swizzle S(k)=k&28 -> conflict-free ds_read_b128.
__global__ __launch_bounds__(256) void k_matmul(const float* __restrict__ x,
                                                const float* __restrict__ W,
                                                const float* __restrict__ a_src,
                                                const float* __restrict__ a_dst,
                                                int N, int nrb, float* __restrict__ xp,
                                                float* __restrict__ al_s,
                                                float* __restrict__ al_d) {
  __shared__ float xs[64 * 64];      // k-major, swizzled (16 KB)
  __shared__ float ws[2][64][64];    // two head tiles (32 KB)
  int tid = threadIdx.x;
  // bijective XCD swizzle: dispatch slot -> logical block
  int nwg = nrb * 8;
  int wg = blockIdx.x;
  int q = nwg >> 3, rm = nwg & 7;
  int xcd = wg & 7, off = wg >> 3;
  int g = (xcd < rm ? xcd * (q + 1) : rm * (q + 1) + (xcd - rm) * q) + off;
  int hp = g & 7;                    // head pair: heads 2*hp, 2*hp+1
  int rb = g >> 3;
  int r0 = rb * 64;
  int c0 = hp * 128;

  for (int idx = tid * 4; idx < 64 * 64; idx += 1024) {
    int r = idx >> 6, c = idx & 63;  // c multiple of 4
    float4 v = make_float4(0.f, 0.f, 0.f, 0.f);
    if (r0 + r < N) v = *(const float4*)&x[(size_t)(r0 + r) * TD + c];
    xs[(c + 0) * 64 + (r ^ ((c + 0) & 28))] = v.x;
    xs[(c + 1) * 64 + (r ^ ((c + 1) & 28))] = v.y;
    xs[(c + 2) * 64 + (r ^ ((c + 2) & 28))] = v.z;
    xs[(c + 3) * 64 + (r ^ ((c + 3) & 28))] = v.w;
    *(float4*)&ws[0][r][c] = *(const float4*)&W[(size_t)r * THC + c0 + c];
    *(float4*)&ws[1][r][c] = *(const float4*)&W[(size_t)r * THC + c0 + 64 + c];
  }
  __syncthreads();

  int ty = tid >> 4, tx = tid & 15;
  float acc[2][4][4] = {};
  for (int k = 0; k < 64; ++k) {
    float4 a  = *(const float4*)&xs[k * 64 + ((ty * 4) ^ (k & 28))];
    float4 b0 = *(const float4*)&ws[0][k][tx * 4];
    float4 b1 = *(const float4*)&ws[1][k][tx * 4];
    acc[0][0][0] += a.x * b0.x; acc[0][0][1] += a.x * b0.y; acc[0][0][2] += a.x * b0.z; acc[0][0][3] += a.x * b0.w;
    acc[0][1][0] += a.y * b0.x; acc[0][1][1] += a.y * b0.y; acc[0][1][2] += a.y * b0.z; acc[0][1][3] += a.y * b0.w;
    acc[0][2][0] += a.z * b0.x; acc[0][2][1] += a.z * b0.y; acc[0][2][2] += a.z * b0.z; acc[0][2][3] += a.z * b0.w;
    acc[0][3][0] += a.w * b0.x; acc[0][3][1] += a.w * b0.y; acc[0][3][2] += a.w * b0.z; acc[0][3][3] += a.w * b0.w;
    acc[1][0][0] += a.x * b1.x; acc[1][0][1] += a.x * b1.y; acc[1][0][2] += a.x * b1.z; acc[1][0][3] += a.x * b1.w;
    acc[1][1][0] += a.y * b1.x; acc[1][1][1] += a.y * b1.y; acc[1][1][2] += a.y * b1.z; acc[1][1][3] += a.y * b1.w;
    acc[1][2][0] += a.z * b1.x; acc[1][2][1] += a.z * b1.y; acc[1][2][2] += a.z * b1.z; acc[1][2][3] += a.z * b1.w;
    acc[1][3][0] += a.w * b1.x; acc[1][3][1] += a.w * b1.y; acc[1][3][2] += a.w * b1.z; acc[1][3][3] += a.w * b1.w;
  }
#pragma unroll
  for (int hh = 0; hh < 2; ++hh) {
    int h = 2 * hp + hh;
    float4 asv = *(const float4*)&a_src[h * TC + tx * 4];
    float4 adv = *(const float4*)&a_dst[h * TC + tx * 4];
#pragma unroll
    for (int i = 0; i < 4; ++i) {
      int r = r0 + ty * 4 + i;
      float ps = acc[hh][i][0] * asv.x + acc[hh][i][1] * asv.y +
                 acc[hh][i][2] * asv.z + acc[hh][i][3] * asv.w;
      float pd = acc[hh][i][0] * adv.x + acc[hh][i][1] * adv.y +
                 acc[hh][i][2] * adv.z + acc[hh][i][3] * adv.w;
      for (int m = 8; m >= 1; m >>= 1) {
        ps += __shfl_xor(ps, m, 16);
        pd += __shfl_xor(pd, m, 16);
      }
      if (r < N) {
        *(float4*)&xp[(size_t)r * THC + h * TC + tx * 4] =
            make_float4(acc[hh][i][0], acc[hh][i][1], acc[hh][i][2], acc[hh][i][3]);
        if (tx == 0) { al_s[r * TH + h] = ps; al_d[r * TH + h] = pd; }
      }
    }
  }
}

// w_e[d,h] = sum_c We[d, h*64+c] * a_e[h,c]
__global__ void k_we(const float* __restrict__ We, const float* __restrict__ a_e,
                     float* __restrict__ w_e) {
  int t = blockIdx.x * blockDim.x + threadIdx.x;
  if (t >= TD * TH) return;
  int d = t >> 4, h = t & 15;
  float s = 0.f;
  for (int c = 0; c < TC; ++c) s += We[(size_t)d * THC + h * TC + c] * a_e[h * TC + c];
  w_e[d * TH + h] = s;
}

// ale[e,h] = <ea_row(e), w_e[:,h]> for REAL edges only (coalesced over e)
__global__ __launch_bounds__(256) void k_al_e(const float* __restrict__ ea,
                                              const float* __restrict__ w_e,
                                              int E, float* __restrict__ ale) {
  __shared__ float sea[16][64];
  __shared__ float swe[TD * TH];
  int tid = threadIdx.x;
  int e0 = blockIdx.x * 16;
  for (int i = tid; i < TD * TH; i += 256) swe[i] = w_e[i];
  {
    int idx = tid * 4;
    int le = idx >> 6, d = idx & 63;
    int e = e0 + le;
    float4 v = make_float4(0.f, 0.f, 0.f, 0.f);
    if (e < E) v = *(const float4*)&ea[(size_t)e * TD + d];
    *(float4*)&sea[le][d] = v;
  }
  __syncthreads();
  int le = tid >> 4, h = tid & 15;
  int e = e0 + le;
  if (e >= E) return;
  float s = 0.f;
  for (int dd = 0; dd < TD; ++dd) {
    int d = (dd + le * 8) & 63;              // rotate start: conflict-free LDS banks
    s += sea[le][d] * swe[d * TH + h];
  }
  ale[(size_t)e * TH + h] = s;
}

// one WAVE per dst node, barrier/LDS-free: lane = h + 16*slot (4 slots).
// Self-loop ale = mean of real in-edge ale (linearity); alpha cached in 4
// named scalars (deg<=16 fully in regs; P(deg>16)~2e-4 recomputes from L2).
// Reductions across slots via __shfl_xor strides 16/32.
__global__ __launch_bounds__(256) void k_att(
    const float* __restrict__ al_s, const float* __restrict__ al_d,
    const float* __restrict__ ale, const int* __restrict__ row_start,
    const int* __restrict__ eid, const int* __restrict__ srcc,
    int E, int N, float* __restrict__ att) {
  int tid = threadIdx.x;
  int n = blockIdx.x * 4 + (tid >> 6);
  if (n >= N) return;
  int lane = tid & 63;
  int h = lane & 15, slot = lane >> 4;
  int beg = row_start[n], end = row_start[n + 1], deg = end - beg;
  float ald = al_d[n * TH + h];

  // pass 1: raw pre-alpha (al_s[src]+ald+ale), cache in 4 scalars; ale-sum
  float a0 = 0.f, a1 = 0.f, a2 = 0.f, a3 = 0.f;
  float asum = 0.f;
  int selfp = -1;
  int cnt = 0;
  for (int p = slot; p < deg; p += 4, ++cnt) {
    int i = beg + p;
    int e = eid[i], s = srcc[i];
    float av = 0.f;
    if (e < E) { av = ale[(size_t)e * TH + h]; asum += av; }
    else selfp = p;                          // exactly one self-loop per node
    float a = al_s[s * TH + h] + ald + av;
    if (cnt == 0) a0 = a; else if (cnt == 1) a1 = a;
    else if (cnt == 2) a2 = a; else if (cnt == 3) a3 = a;
  }
  asum += __shfl_xor(asum, 16);
  asum += __shfl_xor(asum, 32);
  float lale = asum / (float)max(deg - 1, 1);  // mean ale of real in-edges

  auto fin = [&](float a, int p) -> float {  // finalize: self += lale, leaky_relu
    if (p == selfp) a += lale;
    return (a > 0.f) ? a : 0.2f * a;
  };
  auto raw = [&](int p) -> float {           // overflow recompute (deg > 16)
    int i = beg + p;
    int e = eid[i], s = srcc[i];
    float av = (e < E) ? ale[(size_t)e * TH + h] : 0.f;
    return al_s[s * TH + h] + ald + av;
  };

  // pass 2: finalize + max
  float mloc = -1e30f;
  cnt = 0;
  for (int p = slot; p < deg; p += 4, ++cnt) {
    float a;
    if      (cnt == 0) { a0 = fin(a0, p); a = a0; }
    else if (cnt == 1) { a1 = fin(a1, p); a = a1; }
    else if (cnt == 2) { a2 = fin(a2, p); a = a2; }
    else if (cnt == 3) { a3 = fin(a3, p); a = a3; }
    else a = fin(raw(p), p);
    mloc = fmaxf(mloc, a);
  }
  mloc = fmaxf(mloc, __shfl_xor(mloc, 16));
  mloc = fmaxf(mloc, __shfl_xor(mloc, 32));

  // pass 3: denominator
  float dloc = 0.f;
  cnt = 0;
  for (int p = slot; p < deg; p += 4, ++cnt) {
    float a = (cnt == 0) ? a0 : (cnt == 1) ? a1 : (cnt == 2) ? a2 : (cnt == 3) ? a3
              : fin(raw(p), p);
    dloc += expf(a - mloc);
  }
  dloc += __shfl_xor(dloc, 16);
  dloc += __shfl_xor(dloc, 32);
  float dinv = 1.f / (dloc + 1e-16f);

  // pass 4: write normalized attention (64B chunks per position)
  cnt = 0;
  for (int p = slot; p < deg; p += 4, ++cnt) {
    float a = (cnt == 0) ? a0 : (cnt == 1) ? a1 : (cnt == 2) ? a2 : (cnt == 3) ? a3
              : fin(raw(p), p);
    att[(size_t)(beg + p) * TH + h] = expf(a - mloc) * dinv;
  }
}

// src-major: stage xp[s] once in LDS; per out-edge fold heads:
// z[i][c] = sum_h att[i,h] * xp[s,h,c], written in dst-CSR position order.
__global__ __launch_bounds__(256) void k_csc_z(const float* __restrict__ xp,
                                               const float* __restrict__ att,
                                               const int* __restrict__ srow,
                                               const int* __restrict__ smap,
                                               float* __restrict__ z) {
  __shared__ float sx[THC];                  // 4 KB
  int s = blockIdx.x, tid = threadIdx.x;
  int beg = srow[s], end = srow[s + 1];
  *(float4*)&sx[tid * 4] = *(const float4*)&xp[(size_t)s * THC + tid * 4];
  __syncthreads();
  int slot = tid >> 4, c4 = (tid & 15) * 4;
  for (int j = beg + slot; j < end; j += 16) {
    int i = smap[j];
    const float* ar = &att[(size_t)i * TH];
    float4 a0 = *(const float4*)&ar[0];
    float4 a1 = *(const float4*)&ar[4];
    float4 a2 = *(const float4*)&ar[8];
    float4 a3 = *(const float4*)&ar[12];
    float aw[16] = {a0.x, a0.y, a0.z, a0.w, a1.x, a1.y, a1.z, a1.w,
                    a2.x, a2.y, a2.z, a2.w, a3.x, a3.y, a3.z, a3.w};
    float4 acc = make_float4(0.f, 0.f, 0.f, 0.f);
#pragma unroll
    for (int hh = 0; hh < TH; ++hh) {
      float4 v = *(const float4*)&sx[hh * 64 + c4];
      acc.x += aw[hh] * v.x; acc.y += aw[hh] * v.y;
      acc.z += aw[hh] * v.z; acc.w += aw[hh] * v.w;
    }
    *(float4*)&z[(size_t)i * 64 + c4] = acc;
  }
}

// per-dst: sum contiguous z segment, head-mean + bias + relu.
__global__ __launch_bounds__(256) void k_sum_z(const float* __restrict__ z,
                                               const int* __restrict__ row_start,
                                               const float* __restrict__ bias, int N,
                                               float* __restrict__ out) {
  int tid = threadIdx.x;
  int n = blockIdx.x * 16 + (tid >> 4);
  int c4 = (tid & 15) * 4;
  if (n >= N) return;
  int beg = row_start[n], end = row_start[n + 1];
  float4 acc = make_float4(0.f, 0.f, 0.f, 0.f);
  for (int i = beg; i < end; ++i) {
    float4 v = *(const float4*)&z[(size_t)i * 64 + c4];
    acc.x += v.x; acc.y += v.y; acc.z += v.z; acc.w += v.w;
  }
  float4 b = *(const float4*)&bias[c4];
  float4 o;
  o.x = fmaxf(acc.x * (1.0f / TH) + b.x, 0.f);
  o.y = fmaxf(acc.y * (1.0f / TH) + b.y, 0.f);
  o.z = fmaxf(acc.z * (1.0f / TH) + b.z, 0.f);
  o.w = fmaxf(acc.w * (1.0f / TH) + b.w, 0.f);
  *(float4*)&out[(size_t)n * 64 + c4] = o;
}

// ---------------- launch ----------------

extern "C" void kernel_launch(void* const* d_in, const int* in_sizes, int n_in,
                              void* d_out, int out_size, void* d_ws, size_t ws_size,
                              hipStream_t stream) {
  const float* x   = (const float*)d_in[0];
  const int*   ei  = (const int*)d_in[1];
  const float* ea  = (const float*)d_in[2];
  const float* W1  = (const float*)d_in[3];
  const float* as1 = (const float*)d_in[4];
  const float* ad1 = (const float*)d_in[5];
  const float* We1 = (const float*)d_in[6];
  const float* ae1 = (const float*)d_in[7];
  const float* b1  = (const float*)d_in[8];
  const float* W2  = (const float*)d_in[9];
  const float* as2 = (const float*)d_in[10];
  const float* ad2 = (const float*)d_in[11];
  const float* We2 = (const float*)d_in[12];
  const float* ae2 = (const float*)d_in[13];
  const float* b2  = (const float*)d_in[14];

  const int N  = in_sizes[0] / TD;   // 20000
  const int E  = in_sizes[1] / 2;    // 100000
  const int EN = E + N;              // 120000 (with self-loops)
  const int* srcA = ei;
  const int* dstA = ei + E;

  char* w = (char*)d_ws;
  auto alloc = [&](size_t bytes) {
    char* p = w;
    w += (bytes + 255) & ~(size_t)255;
    return p;
  };
  int*   deg2      = (int*)alloc((size_t)2 * N * 4);      // degd | degs
  int*   degd      = deg2;
  int*   degs      = deg2 + N;
  int*   row_start = (int*)alloc((size_t)(N + 1) * 4);
  int*   srow      = (int*)alloc((size_t)(N + 1) * 4);
  int*   cursor    = (int*)alloc((size_t)N * 4);
  int*   scursor   = (int*)alloc((size_t)N * 4);
  int*   eid       = (int*)alloc((size_t)EN * 4);
  int*   srcc      = (int*)alloc((size_t)EN * 4);
  int*   inv       = (int*)alloc((size_t)EN * 4);
  int*   smap      = (int*)alloc((size_t)EN * 4);
  float* xp        = (float*)alloc((size_t)N * THC * 4);  // 82 MB
  float* al_s      = (float*)alloc((size_t)N * TH * 4);
  float* al_d      = (float*)alloc((size_t)N * TH * 4);
  float* ale       = (float*)alloc((size_t)E * TH * 4);   // 6.4 MB, real edges only
  float* att       = (float*)alloc((size_t)EN * TH * 4);  // 7.7 MB
  float* z         = (float*)alloc((size_t)EN * TC * 4);  // 30.7 MB
  float* w_e       = (float*)alloc((size_t)TD * TH * 4);
  float* hbuf      = (float*)ale;  // overlay: ale dead after k_att; layer-2 k_al_e
                                   // rewrites ale only after matmul2 consumed hbuf

  // CSR (by dst) + CSC (by src) build, shared by both layers
  hipMemsetAsync(deg2, 0, (size_t)2 * N * 4, stream);
  k_count2<<<(EN + 255) / 256, 256, 0, stream>>>(srcA, dstA, E, N, degd, degs);
  k_scan2<<<2, 256, 0, stream>>>(degd, N, row_start, cursor, degs, srow, scursor);
  k_scatter_dst<<<(EN + 255) / 256, 256, 0, stream>>>(srcA, dstA, E, N, cursor, eid, srcc, inv);
  k_scatter_src<<<(EN + 255) / 256, 256, 0, stream>>>(srcA, E, N, scursor, inv, smap);

  const int nrb = (N + 63) / 64;     // 313 row blocks
  const int mmgrid = nrb * 8;        // 2504 blocks (2 heads each), XCD-swizzled

  // layer 1
  k_matmul<<<mmgrid, 256, 0, stream>>>(x, W1, as1, ad1, N, nrb, xp, al_s, al_d);
  k_we<<<4, 256, 0, stream>>>(We1, ae1, w_e);
  k_al_e<<<(E + 15) / 16, 256, 0, stream>>>(ea, w_e, E, ale);
  k_att<<<(N + 3) / 4, 256, 0, stream>>>(al_s, al_d, ale, row_start, eid, srcc, E, N, att);
  k_csc_z<<<N, 256, 0, stream>>>(xp, att, srow, smap, z);
  k_sum_z<<<(N + 15) / 16, 256, 0, stream>>>(z, row_start, b1, N, hbuf);

  // layer 2
  k_matmul<<<mmgrid, 256, 0, stream>>>(hbuf, W2, as2, ad2, N, nrb, xp, al_s, al_d);
  k_we<<<4, 256, 0, stream>>>(We2, ae2, w_e);
  k_al_e<<<(E + 15) / 16, 256, 0, stream>>>(ea, w_e, E, ale);
  k_att<<<(N + 3) / 4, 256, 0, stream>>>(al_s, al_d, ale, row_start, eid, srcc, E, N, att);
  k_csc_z<<<N, 256, 0, stream>>>(xp, att, srow, smap, z);
  k_sum_z<<<(N + 15) / 16, 256, 0, stream>>>(z, row_start, b2, N, (float*)d_out);
}

// Round 10
// 307.454 us; speedup vs baseline: 3.0215x; 1.0078x over previous
//
#include <hip/hip_runtime.h>

// GAT (2-layer, PyG GATConv semantics) on MI355X — src-major aggregation.
// N=20000 nodes, E=100000 edges (+N self-loops), D=64, H=16 heads, C=64 ch/head.
constexpr int TD  = 64;      // input feature dim
constexpr int TH  = 16;      // heads
constexpr int TC  = 64;      // channels per head
constexpr int THC = TH * TC; // 1024

// ---------------- CSR/CSC build (once, shared by both layers) ----------------

__global__ void k_count2(const int* __restrict__ src, const int* __restrict__ dst,
                         int E, int N, int* __restrict__ degd, int* __restrict__ degs) {
  int e = blockIdx.x * blockDim.x + threadIdx.x;
  if (e >= E + N) return;
  int s, d;
  if (e < E) { s = src[e]; d = dst[e]; } else { s = d = e - E; }
  atomicAdd(&degd[d], 1);
  atomicAdd(&degs[s], 1);
}

__global__ void k_scan2(const int* __restrict__ degd, int N,
                        int* __restrict__ row_start, int* __restrict__ cursor,
                        const int* __restrict__ degs,
                        int* __restrict__ srow, int* __restrict__ scursor) {
  const int* dg = blockIdx.x ? degs : degd;
  int* rs = blockIdx.x ? srow : row_start;
  int* cu = blockIdx.x ? scursor : cursor;
  __shared__ int part[256];
  int t = threadIdx.x;
  int chunk = (N + 255) / 256;
  int lo = t * chunk, hi = min(lo + chunk, N);
  int s = 0;
  for (int i = lo; i < hi; ++i) s += dg[i];
  part[t] = s;
  __syncthreads();
  if (t == 0) {
    int run = 0;
    for (int i = 0; i < 256; ++i) { int v = part[i]; part[i] = run; run += v; }
    rs[N] = run;
  }
  __syncthreads();
  int run = part[t];
  for (int i = lo; i < hi; ++i) {
    rs[i] = run; cu[i] = run; run += dg[i];
  }
}

__global__ void k_scatter_dst(const int* __restrict__ src, const int* __restrict__ dst,
                              int E, int N, int* __restrict__ cursor,
                              int* __restrict__ eid, int* __restrict__ srcc,
                              int* __restrict__ inv) {
  int e = blockIdx.x * blockDim.x + threadIdx.x;
  if (e >= E + N) return;
  int s, d;
  if (e < E) { s = src[e]; d = dst[e]; } else { s = d = e - E; }
  int pos = atomicAdd(&cursor[d], 1);
  eid[pos] = e; srcc[pos] = s; inv[e] = pos;
}

__global__ void k_scatter_src(const int* __restrict__ src, int E, int N,
                              int* __restrict__ scursor, const int* __restrict__ inv,
                              int* __restrict__ smap) {
  int e = blockIdx.x * blockDim.x + threadIdx.x;
  if (e >= E + N) return;
  int s = (e < E) ? src[e] : (e - E);
  int j = atomicAdd(&scursor[s], 1);
  smap[j] = inv[e];
}

// ---------------- per-layer kernels ----------------

// xp = x[N,64] @ W[64,1024], 128 rows x 2 heads (128 cols) per block, 8x8/thread.
// F/R = 64 FMA / 4 ds_read_b128 = 16 (vs 10.7 before): the k-loop is LDS-pipe
// bound (R9: VALUBusy 48-55% at 3 reads/32 FMA), so fewer reads/FMA is the lever.
// Thread rows split {4ty, 64+4ty}: both reads 2-way-bank (free); 8 contiguous
// rows would be 4-way. W tiles in LDS (R7: register-prefetch spilled).
// Linear grid nrb*8, bijective XCD swizzle (FETCH 3.6 MB, measured R8/R9).
// Fused epilogue: al_s/al_d. x-tile k-major, XOR swizzle S(k)=k&28.
__global__ __launch_bounds__(256) void k_matmul(const float* __restrict__ x,
                                                const float* __restrict__ W,
                                                const float* __restrict__ a_src,
                                                const float* __restrict__ a_dst,
                                                int N, int nrb, float* __restrict__ xp,
                                                float* __restrict__ al_s,
                                                float* __restrict__ al_d) {
  __shared__ float xs[64 * 128];     // k-major, swizzled (32 KB)
  __shared__ float ws[64][128];      // two head tiles side by side (32 KB)
  int tid = threadIdx.x;
  // bijective XCD swizzle
  int nwg = nrb * 8;
  int wg = blockIdx.x;
  int q = nwg >> 3, rm = nwg & 7;
  int xcd = wg & 7, off = wg >> 3;
  int g = (xcd < rm ? xcd * (q + 1) : rm * (q + 1) + (xcd - rm) * q) + off;
  int hp = g & 7;                    // head pair: heads 2*hp, 2*hp+1
  int rb = g >> 3;
  int r0 = rb * 128;
  int c0 = hp * 128;

  for (int idx = tid * 4; idx < 128 * 64; idx += 1024) {
    int r = idx >> 6, c = idx & 63;  // c multiple of 4
    float4 v = make_float4(0.f, 0.f, 0.f, 0.f);
    if (r0 + r < N) v = *(const float4*)&x[(size_t)(r0 + r) * TD + c];
    xs[(c + 0) * 128 + (r ^ ((c + 0) & 28))] = v.x;
    xs[(c + 1) * 128 + (r ^ ((c + 1) & 28))] = v.y;
    xs[(c + 2) * 128 + (r ^ ((c + 2) & 28))] = v.z;
    xs[(c + 3) * 128 + (r ^ ((c + 3) & 28))] = v.w;
  }
  for (int idx = tid * 4; idx < 64 * 128; idx += 1024) {
    int r = idx >> 7, cc = idx & 127;
    *(float4*)&ws[r][cc] = *(const float4*)&W[(size_t)r * THC + c0 + cc];
  }
  __syncthreads();

  int ty = tid >> 4, tx = tid & 15;
  float acc[2][2][4][4] = {};        // [half][head][row][col], fully unrolled below
  for (int k = 0; k < 64; ++k) {
    int swz = (ty * 4) ^ (k & 28);
    float4 aA = *(const float4*)&xs[k * 128 + swz];        // rows 4ty..
    float4 aB = *(const float4*)&xs[k * 128 + 64 + swz];   // rows 64+4ty..
    float4 b0 = *(const float4*)&ws[k][tx * 4];
    float4 b1 = *(const float4*)&ws[k][64 + tx * 4];
    float ar[2][4] = {{aA.x, aA.y, aA.z, aA.w}, {aB.x, aB.y, aB.z, aB.w}};
    float br[2][4] = {{b0.x, b0.y, b0.z, b0.w}, {b1.x, b1.y, b1.z, b1.w}};
#pragma unroll
    for (int hf = 0; hf < 2; ++hf)
#pragma unroll
      for (int hh = 0; hh < 2; ++hh)
#pragma unroll
        for (int i = 0; i < 4; ++i)
#pragma unroll
          for (int j = 0; j < 4; ++j)
            acc[hf][hh][i][j] += ar[hf][i] * br[hh][j];
  }
#pragma unroll
  for (int hh = 0; hh < 2; ++hh) {
    int h = 2 * hp + hh;
    float4 asv = *(const float4*)&a_src[h * TC + tx * 4];
    float4 adv = *(const float4*)&a_dst[h * TC + tx * 4];
#pragma unroll
    for (int hf = 0; hf < 2; ++hf) {
#pragma unroll
      for (int i = 0; i < 4; ++i) {
        int r = r0 + hf * 64 + ty * 4 + i;
        float ps = acc[hf][hh][i][0] * asv.x + acc[hf][hh][i][1] * asv.y +
                   acc[hf][hh][i][2] * asv.z + acc[hf][hh][i][3] * asv.w;
        float pd = acc[hf][hh][i][0] * adv.x + acc[hf][hh][i][1] * adv.y +
                   acc[hf][hh][i][2] * adv.z + acc[hf][hh][i][3] * adv.w;
        for (int m = 8; m >= 1; m >>= 1) {
          ps += __shfl_xor(ps, m, 16);
          pd += __shfl_xor(pd, m, 16);
        }
        if (r < N) {
          *(float4*)&xp[(size_t)r * THC + h * TC + tx * 4] =
              make_float4(acc[hf][hh][i][0], acc[hf][hh][i][1],
                          acc[hf][hh][i][2], acc[hf][hh][i][3]);
          if (tx == 0) { al_s[r * TH + h] = ps; al_d[r * TH + h] = pd; }
        }
      }
    }
  }
}

// w_e for BOTH layers: w_e[layer][d][h] = sum_c We[d, h*64+c] * a_e[h,c]
__global__ void k_we2(const float* __restrict__ We1, const float* __restrict__ ae1,
                      const float* __restrict__ We2, const float* __restrict__ ae2,
                      float* __restrict__ w_e) {
  int t = blockIdx.x * blockDim.x + threadIdx.x;
  if (t >= 2 * TD * TH) return;
  int layer = t >> 10, tt = t & 1023;
  int d = tt >> 4, h = tt & 15;
  const float* We = layer ? We2 : We1;
  const float* ae = layer ? ae2 : ae1;
  float s = 0.f;
  for (int c = 0; c < TC; ++c) s += We[(size_t)d * THC + h * TC + c] * ae[h * TC + c];
  w_e[t] = s;
}

// ale[e,h] for BOTH layers (blockIdx.y = layer), real edges, coalesced over e
__global__ __launch_bounds__(256) void k_al_e2(const float* __restrict__ ea,
                                               const float* __restrict__ w_e,
                                               int E, float* __restrict__ ale1,
                                               float* __restrict__ ale2) {
  __shared__ float sea[16][64];
  __shared__ float swe[TD * TH];
  int tid = threadIdx.x;
  int e0 = blockIdx.x * 16;
  const float* we = w_e + blockIdx.y * (TD * TH);
  float* ale = blockIdx.y ? ale2 : ale1;
  for (int i = tid; i < TD * TH; i += 256) swe[i] = we[i];
  {
    int idx = tid * 4;
    int le = idx >> 6, d = idx & 63;
    int e = e0 + le;
    float4 v = make_float4(0.f, 0.f, 0.f, 0.f);
    if (e < E) v = *(const float4*)&ea[(size_t)e * TD + d];
    *(float4*)&sea[le][d] = v;
  }
  __syncthreads();
  int le = tid >> 4, h = tid & 15;
  int e = e0 + le;
  if (e >= E) return;
  float s = 0.f;
  for (int dd = 0; dd < TD; ++dd) {
    int d = (dd + le * 8) & 63;              // rotate start: conflict-free LDS banks
    s += sea[le][d] * swe[d * TH + h];
  }
  ale[(size_t)e * TH + h] = s;
}

// one WAVE per dst node, barrier/LDS-free (measured win R9): lane = h + 16*slot.
__global__ __launch_bounds__(256) void k_att(
    const float* __restrict__ al_s, const float* __restrict__ al_d,
    const float* __restrict__ ale, const int* __restrict__ row_start,
    const int* __restrict__ eid, const int* __restrict__ srcc,
    int E, int N, float* __restrict__ att) {
  int tid = threadIdx.x;
  int n = blockIdx.x * 4 + (tid >> 6);
  if (n >= N) return;
  int lane = tid & 63;
  int h = lane & 15, slot = lane >> 4;
  int beg = row_start[n], end = row_start[n + 1], deg = end - beg;
  float ald = al_d[n * TH + h];

  float a0 = 0.f, a1 = 0.f, a2 = 0.f, a3 = 0.f;
  float asum = 0.f;
  int selfp = -1;
  int cnt = 0;
  for (int p = slot; p < deg; p += 4, ++cnt) {
    int i = beg + p;
    int e = eid[i], s = srcc[i];
    float av = 0.f;
    if (e < E) { av = ale[(size_t)e * TH + h]; asum += av; }
    else selfp = p;
    float a = al_s[s * TH + h] + ald + av;
    if (cnt == 0) a0 = a; else if (cnt == 1) a1 = a;
    else if (cnt == 2) a2 = a; else if (cnt == 3) a3 = a;
  }
  asum += __shfl_xor(asum, 16);
  asum += __shfl_xor(asum, 32);
  float lale = asum / (float)max(deg - 1, 1);

  auto fin = [&](float a, int p) -> float {
    if (p == selfp) a += lale;
    return (a > 0.f) ? a : 0.2f * a;
  };
  auto raw = [&](int p) -> float {
    int i = beg + p;
    int e = eid[i], s = srcc[i];
    float av = (e < E) ? ale[(size_t)e * TH + h] : 0.f;
    return al_s[s * TH + h] + ald + av;
  };

  float mloc = -1e30f;
  cnt = 0;
  for (int p = slot; p < deg; p += 4, ++cnt) {
    float a;
    if      (cnt == 0) { a0 = fin(a0, p); a = a0; }
    else if (cnt == 1) { a1 = fin(a1, p); a = a1; }
    else if (cnt == 2) { a2 = fin(a2, p); a = a2; }
    else if (cnt == 3) { a3 = fin(a3, p); a = a3; }
    else a = fin(raw(p), p);
    mloc = fmaxf(mloc, a);
  }
  mloc = fmaxf(mloc, __shfl_xor(mloc, 16));
  mloc = fmaxf(mloc, __shfl_xor(mloc, 32));

  float dloc = 0.f;
  cnt = 0;
  for (int p = slot; p < deg; p += 4, ++cnt) {
    float a = (cnt == 0) ? a0 : (cnt == 1) ? a1 : (cnt == 2) ? a2 : (cnt == 3) ? a3
              : fin(raw(p), p);
    dloc += expf(a - mloc);
  }
  dloc += __shfl_xor(dloc, 16);
  dloc += __shfl_xor(dloc, 32);
  float dinv = 1.f / (dloc + 1e-16f);

  cnt = 0;
  for (int p = slot; p < deg; p += 4, ++cnt) {
    float a = (cnt == 0) ? a0 : (cnt == 1) ? a1 : (cnt == 2) ? a2 : (cnt == 3) ? a3
              : fin(raw(p), p);
    att[(size_t)(beg + p) * TH + h] = expf(a - mloc) * dinv;
  }
}

// src-major, LDS/barrier-free: one WAVE per src node. Each lane keeps its 16-head
// xp slice (16 float4 = 64 VGPR) and serves 4 edge-slots.
// z[i][c] = sum_h att[i,h]*xp[s,h,c], dst-CSR position order.
__global__ __launch_bounds__(256) void k_csc_z(const float* __restrict__ xp,
                                               const float* __restrict__ att,
                                               const int* __restrict__ srow,
                                               const int* __restrict__ smap,
                                               int N, float* __restrict__ z) {
  int tid = threadIdx.x;
  int s = blockIdx.x * 4 + (tid >> 6);
  if (s >= N) return;
  int lane = tid & 63;
  int slot = lane >> 4, c4 = (lane & 15) * 4;
  float4 xf[16];
#pragma unroll
  for (int h = 0; h < TH; ++h)
    xf[h] = *(const float4*)&xp[(size_t)s * THC + h * 64 + c4];
  int beg = srow[s], end = srow[s + 1];
  for (int j = beg + slot; j < end; j += 4) {
    int i = smap[j];
    const float* ar = &att[(size_t)i * TH];
    float4 a0 = *(const float4*)&ar[0];
    float4 a1 = *(const float4*)&ar[4];
    float4 a2 = *(const float4*)&ar[8];
    float4 a3 = *(const float4*)&ar[12];
    float aw[16] = {a0.x, a0.y, a0.z, a0.w, a1.x, a1.y, a1.z, a1.w,
                    a2.x, a2.y, a2.z, a2.w, a3.x, a3.y, a3.z, a3.w};
    float4 acc = make_float4(0.f, 0.f, 0.f, 0.f);
#pragma unroll
    for (int hh = 0; hh < TH; ++hh) {
      acc.x += aw[hh] * xf[hh].x; acc.y += aw[hh] * xf[hh].y;
      acc.z += aw[hh] * xf[hh].z; acc.w += aw[hh] * xf[hh].w;
    }
    *(float4*)&z[(size_t)i * 64 + c4] = acc;
  }
}

// per-dst: sum contiguous z segment, head-mean + bias + relu.
__global__ __launch_bounds__(256) void k_sum_z(const float* __restrict__ z,
                                               const int* __restrict__ row_start,
                                               const float* __restrict__ bias, int N,
                                               float* __restrict__ out) {
  int tid = threadIdx.x;
  int n = blockIdx.x * 16 + (tid >> 4);
  int c4 = (tid & 15) * 4;
  if (n >= N) return;
  int beg = row_start[n], end = row_start[n + 1];
  float4 acc = make_float4(0.f, 0.f, 0.f, 0.f);
  for (int i = beg; i < end; ++i) {
    float4 v = *(const float4*)&z[(size_t)i * 64 + c4];
    acc.x += v.x; acc.y += v.y; acc.z += v.z; acc.w += v.w;
  }
  float4 b = *(const float4*)&bias[c4];
  float4 o;
  o.x = fmaxf(acc.x * (1.0f / TH) + b.x, 0.f);
  o.y = fmaxf(acc.y * (1.0f / TH) + b.y, 0.f);
  o.z = fmaxf(acc.z * (1.0f / TH) + b.z, 0.f);
  o.w = fmaxf(acc.w * (1.0f / TH) + b.w, 0.f);
  *(float4*)&out[(size_t)n * 64 + c4] = o;
}

// ---------------- launch ----------------

extern "C" void kernel_launch(void* const* d_in, const int* in_sizes, int n_in,
                              void* d_out, int out_size, void* d_ws, size_t ws_size,
                              hipStream_t stream) {
  const float* x   = (const float*)d_in[0];
  const int*   ei  = (const int*)d_in[1];
  const float* ea  = (const float*)d_in[2];
  const float* W1  = (const float*)d_in[3];
  const float* as1 = (const float*)d_in[4];
  const float* ad1 = (const float*)d_in[5];
  const float* We1 = (const float*)d_in[6];
  const float* ae1 = (const float*)d_in[7];
  const float* b1  = (const float*)d_in[8];
  const float* W2  = (const float*)d_in[9];
  const float* as2 = (const float*)d_in[10];
  const float* ad2 = (const float*)d_in[11];
  const float* We2 = (const float*)d_in[12];
  const float* ae2 = (const float*)d_in[13];
  const float* b2  = (const float*)d_in[14];

  const int N  = in_sizes[0] / TD;   // 20000
  const int E  = in_sizes[1] / 2;    // 100000
  const int EN = E + N;              // 120000 (with self-loops)
  const int* srcA = ei;
  const int* dstA = ei + E;

  char* w = (char*)d_ws;
  auto alloc = [&](size_t bytes) {
    char* p = w;
    w += (bytes + 255) & ~(size_t)255;
    return p;
  };
  int*   deg2      = (int*)alloc((size_t)2 * N * 4);      // degd | degs
  int*   degd      = deg2;
  int*   degs      = deg2 + N;
  int*   row_start = (int*)alloc((size_t)(N + 1) * 4);
  int*   srow      = (int*)alloc((size_t)(N + 1) * 4);
  int*   cursor    = (int*)alloc((size_t)N * 4);
  int*   scursor   = (int*)alloc((size_t)N * 4);
  int*   eid       = (int*)alloc((size_t)EN * 4);
  int*   srcc      = (int*)alloc((size_t)EN * 4);
  int*   inv       = (int*)alloc((size_t)EN * 4);
  int*   smap      = (int*)alloc((size_t)EN * 4);
  float* xp        = (float*)alloc((size_t)N * THC * 4);  // 82 MB
  float* al_s      = (float*)alloc((size_t)N * TH * 4);
  float* al_d      = (float*)alloc((size_t)N * TH * 4);
  float* ale1      = (float*)alloc((size_t)E * TH * 4);   // 6.4 MB
  float* ale2      = (float*)alloc((size_t)E * TH * 4);   // 6.4 MB
  float* att       = (float*)alloc((size_t)EN * TH * 4);  // 7.7 MB
  float* z         = (float*)alloc((size_t)EN * TC * 4);  // 30.7 MB
  float* w_e       = (float*)alloc((size_t)2 * TD * TH * 4);
  float* hbuf      = (float*)ale1; // overlay: ale1 dead after k_att layer 1;
                                   // layer-2 uses ale2 (separate)

  // CSR (by dst) + CSC (by src) build, shared by both layers
  hipMemsetAsync(deg2, 0, (size_t)2 * N * 4, stream);
  k_count2<<<(EN + 255) / 256, 256, 0, stream>>>(srcA, dstA, E, N, degd, degs);
  k_scan2<<<2, 256, 0, stream>>>(degd, N, row_start, cursor, degs, srow, scursor);
  k_scatter_dst<<<(EN + 255) / 256, 256, 0, stream>>>(srcA, dstA, E, N, cursor, eid, srcc, inv);
  k_scatter_src<<<(EN + 255) / 256, 256, 0, stream>>>(srcA, E, N, scursor, inv, smap);

  // edge-attention logits for BOTH layers up-front (depend only on ea, We, ae)
  k_we2<<<8, 256, 0, stream>>>(We1, ae1, We2, ae2, w_e);
  dim3 aleg((E + 15) / 16, 2);
  k_al_e2<<<aleg, 256, 0, stream>>>(ea, w_e, E, ale1, ale2);

  const int nrb = (N + 127) / 128;   // 157 row blocks
  const int mmgrid = nrb * 8;        // 1256 blocks (128 rows x 2 heads), XCD-swizzled

  // layer 1
  k_matmul<<<mmgrid, 256, 0, stream>>>(x, W1, as1, ad1, N, nrb, xp, al_s, al_d);
  k_att<<<(N + 3) / 4, 256, 0, stream>>>(al_s, al_d, ale1, row_start, eid, srcc, E, N, att);
  k_csc_z<<<(N + 3) / 4, 256, 0, stream>>>(xp, att, srow, smap, N, z);
  k_sum_z<<<(N + 15) / 16, 256, 0, stream>>>(z, row_start, b1, N, hbuf);

  // layer 2
  k_matmul<<<mmgrid, 256, 0, stream>>>(hbuf, W2, as2, ad2, N, nrb, xp, al_s, al_d);
  k_att<<<(N + 3) / 4, 256, 0, stream>>>(al_s, al_d, ale2, row_start, eid, srcc, E, N, att);
  k_csc_z<<<(N + 3) / 4, 256, 0, stream>>>(xp, att, srow, smap, N, z);
  k_sum_z<<<(N + 15) / 16, 256, 0, stream>>>(z, row_start, b2, N, (float*)d_out);
}

// Round 12
// 298.623 us; speedup vs baseline: 3.1108x; 1.0296x over previous
//
#include <hip/hip_runtime.h>

// GAT (2-layer, PyG GATConv semantics) on MI355X — src-major aggregation.
// N=20000 nodes, E=100000 edges (+N self-loops), D=64, H=16 heads, C=64 ch/head.
constexpr int TD  = 64;      // input feature dim
constexpr int TH  = 16;      // heads
constexpr int TC  = 64;      // channels per head
constexpr int THC = TH * TC; // 1024

// ---------------- CSR/CSC build (once, shared by both layers) ----------------

__global__ void k_count2(const int* __restrict__ src, const int* __restrict__ dst,
                         int E, int N, int* __restrict__ degd, int* __restrict__ degs) {
  int e = blockIdx.x * blockDim.x + threadIdx.x;
  if (e >= E + N) return;
  int s, d;
  if (e < E) { s = src[e]; d = dst[e]; } else { s = d = e - E; }
  atomicAdd(&degd[d], 1);
  atomicAdd(&degs[s], 1);
}

__global__ void k_scan2(const int* __restrict__ degd, int N,
                        int* __restrict__ row_start, int* __restrict__ cursor,
                        const int* __restrict__ degs,
                        int* __restrict__ srow, int* __restrict__ scursor) {
  const int* dg = blockIdx.x ? degs : degd;
  int* rs = blockIdx.x ? srow : row_start;
  int* cu = blockIdx.x ? scursor : cursor;
  __shared__ int part[256];
  int t = threadIdx.x;
  int chunk = (N + 255) / 256;
  int lo = t * chunk, hi = min(lo + chunk, N);
  int s = 0;
  for (int i = lo; i < hi; ++i) s += dg[i];
  part[t] = s;
  __syncthreads();
  if (t == 0) {
    int run = 0;
    for (int i = 0; i < 256; ++i) { int v = part[i]; part[i] = run; run += v; }
    rs[N] = run;
  }
  __syncthreads();
  int run = part[t];
  for (int i = lo; i < hi; ++i) {
    rs[i] = run; cu[i] = run; run += dg[i];
  }
}

__global__ void k_scatter_dst(const int* __restrict__ src, const int* __restrict__ dst,
                              int E, int N, int* __restrict__ cursor,
                              int* __restrict__ eid, int* __restrict__ srcc,
                              int* __restrict__ inv) {
  int e = blockIdx.x * blockDim.x + threadIdx.x;
  if (e >= E + N) return;
  int s, d;
  if (e < E) { s = src[e]; d = dst[e]; } else { s = d = e - E; }
  int pos = atomicAdd(&cursor[d], 1);
  eid[pos] = e; srcc[pos] = s; inv[e] = pos;
}

__global__ void k_scatter_src(const int* __restrict__ src, int E, int N,
                              int* __restrict__ scursor, const int* __restrict__ inv,
                              int* __restrict__ smap) {
  int e = blockIdx.x * blockDim.x + threadIdx.x;
  if (e >= E + N) return;
  int s = (e < E) ? src[e] : (e - E);
  int j = atomicAdd(&scursor[s], 1);
  smap[j] = inv[e];
}

// ---------------- per-layer kernels ----------------

// xp = x[N,64] @ W[64,1024], 128 rows x 2 heads (128 cols) per block, 8x8/thread,
// K split into 2 halves of 32 so LDS = 32 KB (16 KB xs + 16 KB ws) -> 5 blocks/CU.
// R10 lesson: same tile at 64 KB LDS = 2 blocks/CU -> latency-bound (VALU 37%).
// F/R = 64 FMA / 4 ds_read_b128 = 16 (R8/R9's 8-10.7 was LDS-pipe-bound at ~50%).
// W tiles via LDS (R7: register-prefetch spilled). Bijective XCD swizzle
// (FETCH 3.6 MB measured R8/R9). Fused epilogue: al_s/al_d.
// x-tile k-major, XOR swizzle S(kk)=kk&28 -> conflict-free ds_read_b128.
__global__ __launch_bounds__(256) void k_matmul(const float* __restrict__ x,
                                                const float* __restrict__ W,
                                                const float* __restrict__ a_src,
                                                const float* __restrict__ a_dst,
                                                int N, int nrb, float* __restrict__ xp,
                                                float* __restrict__ al_s,
                                                float* __restrict__ al_d) {
  __shared__ float xs[32 * 128];     // k-half-major, swizzled (16 KB)
  __shared__ float ws[32][128];      // k-half x two heads (16 KB)
  int tid = threadIdx.x;
  // bijective XCD swizzle
  int nwg = nrb * 8;
  int wg = blockIdx.x;
  int q = nwg >> 3, rm = nwg & 7;
  int xcd = wg & 7, off = wg >> 3;
  int g = (xcd < rm ? xcd * (q + 1) : rm * (q + 1) + (xcd - rm) * q) + off;
  int hp = g & 7;                    // head pair: heads 2*hp, 2*hp+1
  int rb = g >> 3;
  int r0 = rb * 128;
  int c0 = hp * 128;

  int ty = tid >> 4, tx = tid & 15;
  float acc[2][2][4][4] = {};        // [row-half][head][row][col]

  for (int kh = 0; kh < 2; ++kh) {
    if (kh) __syncthreads();         // protect LDS from overwrite mid-compute
    // stage x k-half: 128 rows x 32 k (4 float4/thread)
    for (int idx = tid * 4; idx < 128 * 32; idx += 1024) {
      int r = idx >> 5, c = idx & 31;          // c multiple of 4
      float4 v = make_float4(0.f, 0.f, 0.f, 0.f);
      if (r0 + r < N) v = *(const float4*)&x[(size_t)(r0 + r) * TD + kh * 32 + c];
      xs[(c + 0) * 128 + (r ^ ((c + 0) & 28))] = v.x;
      xs[(c + 1) * 128 + (r ^ ((c + 1) & 28))] = v.y;
      xs[(c + 2) * 128 + (r ^ ((c + 2) & 28))] = v.z;
      xs[(c + 3) * 128 + (r ^ ((c + 3) & 28))] = v.w;
    }
    // stage W k-half: 32 k x 128 cols (4 float4/thread)
    for (int idx = tid * 4; idx < 32 * 128; idx += 1024) {
      int r = idx >> 7, cc = idx & 127;
      *(float4*)&ws[r][cc] = *(const float4*)&W[(size_t)(kh * 32 + r) * THC + c0 + cc];
    }
    __syncthreads();

    for (int kk = 0; kk < 32; ++kk) {
      int swz = (ty * 4) ^ (kk & 28);
      float4 aA = *(const float4*)&xs[kk * 128 + swz];        // rows 4ty..
      float4 aB = *(const float4*)&xs[kk * 128 + 64 + swz];   // rows 64+4ty..
      float4 b0 = *(const float4*)&ws[kk][tx * 4];
      float4 b1 = *(const float4*)&ws[kk][64 + tx * 4];
      float ar[2][4] = {{aA.x, aA.y, aA.z, aA.w}, {aB.x, aB.y, aB.z, aB.w}};
      float br[2][4] = {{b0.x, b0.y, b0.z, b0.w}, {b1.x, b1.y, b1.z, b1.w}};
#pragma unroll
      for (int hf = 0; hf < 2; ++hf)
#pragma unroll
        for (int hh = 0; hh < 2; ++hh)
#pragma unroll
          for (int i = 0; i < 4; ++i)
#pragma unroll
            for (int j = 0; j < 4; ++j)
              acc[hf][hh][i][j] += ar[hf][i] * br[hh][j];
    }
  }

#pragma unroll
  for (int hh = 0; hh < 2; ++hh) {
    int h = 2 * hp + hh;
    float4 asv = *(const float4*)&a_src[h * TC + tx * 4];
    float4 adv = *(const float4*)&a_dst[h * TC + tx * 4];
#pragma unroll
    for (int hf = 0; hf < 2; ++hf) {
#pragma unroll
      for (int i = 0; i < 4; ++i) {
        int r = r0 + hf * 64 + ty * 4 + i;
        float ps = acc[hf][hh][i][0] * asv.x + acc[hf][hh][i][1] * asv.y +
                   acc[hf][hh][i][2] * asv.z + acc[hf][hh][i][3] * asv.w;
        float pd = acc[hf][hh][i][0] * adv.x + acc[hf][hh][i][1] * adv.y +
                   acc[hf][hh][i][2] * adv.z + acc[hf][hh][i][3] * adv.w;
        for (int m = 8; m >= 1; m >>= 1) {
          ps += __shfl_xor(ps, m, 16);
          pd += __shfl_xor(pd, m, 16);
        }
        if (r < N) {
          *(float4*)&xp[(size_t)r * THC + h * TC + tx * 4] =
              make_float4(acc[hf][hh][i][0], acc[hf][hh][i][1],
                          acc[hf][hh][i][2], acc[hf][hh][i][3]);
          if (tx == 0) { al_s[r * TH + h] = ps; al_d[r * TH + h] = pd; }
        }
      }
    }
  }
}

// w_e for BOTH layers: w_e[layer][d][h] = sum_c We[d, h*64+c] * a_e[h,c]
__global__ void k_we2(const float* __restrict__ We1, const float* __restrict__ ae1,
                      const float* __restrict__ We2, const float* __restrict__ ae2,
                      float* __restrict__ w_e) {
  int t = blockIdx.x * blockDim.x + threadIdx.x;
  if (t >= 2 * TD * TH) return;
  int layer = t >> 10, tt = t & 1023;
  int d = tt >> 4, h = tt & 15;
  const float* We = layer ? We2 : We1;
  const float* ae = layer ? ae2 : ae1;
  float s = 0.f;
  for (int c = 0; c < TC; ++c) s += We[(size_t)d * THC + h * TC + c] * ae[h * TC + c];
  w_e[t] = s;
}

// ale[e,h] for BOTH layers (blockIdx.y = layer), real edges, coalesced over e
__global__ __launch_bounds__(256) void k_al_e2(const float* __restrict__ ea,
                                               const float* __restrict__ w_e,
                                               int E, float* __restrict__ ale1,
                                               float* __restrict__ ale2) {
  __shared__ float sea[16][64];
  __shared__ float swe[TD * TH];
  int tid = threadIdx.x;
  int e0 = blockIdx.x * 16;
  const float* we = w_e + blockIdx.y * (TD * TH);
  float* ale = blockIdx.y ? ale2 : ale1;
  for (int i = tid; i < TD * TH; i += 256) swe[i] = we[i];
  {
    int idx = tid * 4;
    int le = idx >> 6, d = idx & 63;
    int e = e0 + le;
    float4 v = make_float4(0.f, 0.f, 0.f, 0.f);
    if (e < E) v = *(const float4*)&ea[(size_t)e * TD + d];
    *(float4*)&sea[le][d] = v;
  }
  __syncthreads();
  int le = tid >> 4, h = tid & 15;
  int e = e0 + le;
  if (e >= E) return;
  float s = 0.f;
  for (int dd = 0; dd < TD; ++dd) {
    int d = (dd + le * 8) & 63;              // rotate start: conflict-free LDS banks
    s += sea[le][d] * swe[d * TH + h];
  }
  ale[(size_t)e * TH + h] = s;
}

// one WAVE per dst node, barrier/LDS-free (measured win R9): lane = h + 16*slot.
__global__ __launch_bounds__(256) void k_att(
    const float* __restrict__ al_s, const float* __restrict__ al_d,
    const float* __restrict__ ale, const int* __restrict__ row_start,
    const int* __restrict__ eid, const int* __restrict__ srcc,
    int E, int N, float* __restrict__ att) {
  int tid = threadIdx.x;
  int n = blockIdx.x * 4 + (tid >> 6);
  if (n >= N) return;
  int lane = tid & 63;
  int h = lane & 15, slot = lane >> 4;
  int beg = row_start[n], end = row_start[n + 1], deg = end - beg;
  float ald = al_d[n * TH + h];

  float a0 = 0.f, a1 = 0.f, a2 = 0.f, a3 = 0.f;
  float asum = 0.f;
  int selfp = -1;
  int cnt = 0;
  for (int p = slot; p < deg; p += 4, ++cnt) {
    int i = beg + p;
    int e = eid[i], s = srcc[i];
    float av = 0.f;
    if (e < E) { av = ale[(size_t)e * TH + h]; asum += av; }
    else selfp = p;
    float a = al_s[s * TH + h] + ald + av;
    if (cnt == 0) a0 = a; else if (cnt == 1) a1 = a;
    else if (cnt == 2) a2 = a; else if (cnt == 3) a3 = a;
  }
  asum += __shfl_xor(asum, 16);
  asum += __shfl_xor(asum, 32);
  float lale = asum / (float)max(deg - 1, 1);

  auto fin = [&](float a, int p) -> float {
    if (p == selfp) a += lale;
    return (a > 0.f) ? a : 0.2f * a;
  };
  auto raw = [&](int p) -> float {
    int i = beg + p;
    int e = eid[i], s = srcc[i];
    float av = (e < E) ? ale[(size_t)e * TH + h] : 0.f;
    return al_s[s * TH + h] + ald + av;
  };

  float mloc = -1e30f;
  cnt = 0;
  for (int p = slot; p < deg; p += 4, ++cnt) {
    float a;
    if      (cnt == 0) { a0 = fin(a0, p); a = a0; }
    else if (cnt == 1) { a1 = fin(a1, p); a = a1; }
    else if (cnt == 2) { a2 = fin(a2, p); a = a2; }
    else if (cnt == 3) { a3 = fin(a3, p); a = a3; }
    else a = fin(raw(p), p);
    mloc = fmaxf(mloc, a);
  }
  mloc = fmaxf(mloc, __shfl_xor(mloc, 16));
  mloc = fmaxf(mloc, __shfl_xor(mloc, 32));

  float dloc = 0.f;
  cnt = 0;
  for (int p = slot; p < deg; p += 4, ++cnt) {
    float a = (cnt == 0) ? a0 : (cnt == 1) ? a1 : (cnt == 2) ? a2 : (cnt == 3) ? a3
              : fin(raw(p), p);
    dloc += expf(a - mloc);
  }
  dloc += __shfl_xor(dloc, 16);
  dloc += __shfl_xor(dloc, 32);
  float dinv = 1.f / (dloc + 1e-16f);

  cnt = 0;
  for (int p = slot; p < deg; p += 4, ++cnt) {
    float a = (cnt == 0) ? a0 : (cnt == 1) ? a1 : (cnt == 2) ? a2 : (cnt == 3) ? a3
              : fin(raw(p), p);
    att[(size_t)(beg + p) * TH + h] = expf(a - mloc) * dinv;
  }
}

// src-major, LDS/barrier-free: one WAVE per src node. Each lane keeps its 16-head
// xp slice (16 float4 = 64 VGPR) and serves 4 edge-slots.
// z[i][c] = sum_h att[i,h]*xp[s,h,c], dst-CSR position order.
__global__ __launch_bounds__(256) void k_csc_z(const float* __restrict__ xp,
                                               const float* __restrict__ att,
                                               const int* __restrict__ srow,
                                               const int* __restrict__ smap,
                                               int N, float* __restrict__ z) {
  int tid = threadIdx.x;
  int s = blockIdx.x * 4 + (tid >> 6);
  if (s >= N) return;
  int lane = tid & 63;
  int slot = lane >> 4, c4 = (lane & 15) * 4;
  float4 xf[16];
#pragma unroll
  for (int h = 0; h < TH; ++h)
    xf[h] = *(const float4*)&xp[(size_t)s * THC + h * 64 + c4];
  int beg = srow[s], end = srow[s + 1];
  for (int j = beg + slot; j < end; j += 4) {
    int i = smap[j];
    const float* ar = &att[(size_t)i * TH];
    float4 a0 = *(const float4*)&ar[0];
    float4 a1 = *(const float4*)&ar[4];
    float4 a2 = *(const float4*)&ar[8];
    float4 a3 = *(const float4*)&ar[12];
    float aw[16] = {a0.x, a0.y, a0.z, a0.w, a1.x, a1.y, a1.z, a1.w,
                    a2.x, a2.y, a2.z, a2.w, a3.x, a3.y, a3.z, a3.w};
    float4 acc = make_float4(0.f, 0.f, 0.f, 0.f);
#pragma unroll
    for (int hh = 0; hh < TH; ++hh) {
      acc.x += aw[hh] * xf[hh].x; acc.y += aw[hh] * xf[hh].y;
      acc.z += aw[hh] * xf[hh].z; acc.w += aw[hh] * xf[hh].w;
    }
    *(float4*)&z[(size_t)i * 64 + c4] = acc;
  }
}

// per-dst: sum contiguous z segment, head-mean + bias + relu.
__global__ __launch_bounds__(256) void k_sum_z(const float* __restrict__ z,
                                               const int* __restrict__ row_start,
                                               const float* __restrict__ bias, int N,
                                               float* __restrict__ out) {
  int tid = threadIdx.x;
  int n = blockIdx.x * 16 + (tid >> 4);
  int c4 = (tid & 15) * 4;
  if (n >= N) return;
  int beg = row_start[n], end = row_start[n + 1];
  float4 acc = make_float4(0.f, 0.f, 0.f, 0.f);
  for (int i = beg; i < end; ++i) {
    float4 v = *(const float4*)&z[(size_t)i * 64 + c4];
    acc.x += v.x; acc.y += v.y; acc.z += v.z; acc.w += v.w;
  }
  float4 b = *(const float4*)&bias[c4];
  float4 o;
  o.x = fmaxf(acc.x * (1.0f / TH) + b.x, 0.f);
  o.y = fmaxf(acc.y * (1.0f / TH) + b.y, 0.f);
  o.z = fmaxf(acc.z * (1.0f / TH) + b.z, 0.f);
  o.w = fmaxf(acc.w * (1.0f / TH) + b.w, 0.f);
  *(float4*)&out[(size_t)n * 64 + c4] = o;
}

// ---------------- launch ----------------

extern "C" void kernel_launch(void* const* d_in, const int* in_sizes, int n_in,
                              void* d_out, int out_size, void* d_ws, size_t ws_size,
                              hipStream_t stream) {
  const float* x   = (const float*)d_in[0];
  const int*   ei  = (const int*)d_in[1];
  const float* ea  = (const float*)d_in[2];
  const float* W1  = (const float*)d_in[3];
  const float* as1 = (const float*)d_in[4];
  const float* ad1 = (const float*)d_in[5];
  const float* We1 = (const float*)d_in[6];
  const float* ae1 = (const float*)d_in[7];
  const float* b1  = (const float*)d_in[8];
  const float* W2  = (const float*)d_in[9];
  const float* as2 = (const float*)d_in[10];
  const float* ad2 = (const float*)d_in[11];
  const float* We2 = (const float*)d_in[12];
  const float* ae2 = (const float*)d_in[13];
  const float* b2  = (const float*)d_in[14];

  const int N  = in_sizes[0] / TD;   // 20000
  const int E  = in_sizes[1] / 2;    // 100000
  const int EN = E + N;              // 120000 (with self-loops)
  const int* srcA = ei;
  const int* dstA = ei + E;

  char* w = (char*)d_ws;
  auto alloc = [&](size_t bytes) {
    char* p = w;
    w += (bytes + 255) & ~(size_t)255;
    return p;
  };
  int*   deg2      = (int*)alloc((size_t)2 * N * 4);      // degd | degs
  int*   degd      = deg2;
  int*   degs      = deg2 + N;
  int*   row_start = (int*)alloc((size_t)(N + 1) * 4);
  int*   srow      = (int*)alloc((size_t)(N + 1) * 4);
  int*   cursor    = (int*)alloc((size_t)N * 4);
  int*   scursor   = (int*)alloc((size_t)N * 4);
  int*   eid       = (int*)alloc((size_t)EN * 4);
  int*   srcc      = (int*)alloc((size_t)EN * 4);
  int*   inv       = (int*)alloc((size_t)EN * 4);
  int*   smap      = (int*)alloc((size_t)EN * 4);
  float* xp        = (float*)alloc((size_t)N * THC * 4);  // 82 MB
  float* al_s      = (float*)alloc((size_t)N * TH * 4);
  float* al_d      = (float*)alloc((size_t)N * TH * 4);
  float* ale1      = (float*)alloc((size_t)E * TH * 4);   // 6.4 MB
  float* ale2      = (float*)alloc((size_t)E * TH * 4);   // 6.4 MB
  float* att       = (float*)alloc((size_t)EN * TH * 4);  // 7.7 MB
  float* z         = (float*)alloc((size_t)EN * TC * 4);  // 30.7 MB
  float* w_e       = (float*)alloc((size_t)2 * TD * TH * 4);
  float* hbuf      = (float*)ale1; // overlay: ale1 dead after k_att layer 1;
                                   // layer-2 uses ale2 (separate)

  // CSR (by dst) + CSC (by src) build, shared by both layers
  hipMemsetAsync(deg2, 0, (size_t)2 * N * 4, stream);
  k_count2<<<(EN + 255) / 256, 256, 0, stream>>>(srcA, dstA, E, N, degd, degs);
  k_scan2<<<2, 256, 0, stream>>>(degd, N, row_start, cursor, degs, srow, scursor);
  k_scatter_dst<<<(EN + 255) / 256, 256, 0, stream>>>(srcA, dstA, E, N, cursor, eid, srcc, inv);
  k_scatter_src<<<(EN + 255) / 256, 256, 0, stream>>>(srcA, E, N, scursor, inv, smap);

  // edge-attention logits for BOTH layers up-front (depend only on ea, We, ae)
  k_we2<<<8, 256, 0, stream>>>(We1, ae1, We2, ae2, w_e);
  dim3 aleg((E + 15) / 16, 2);
  k_al_e2<<<aleg, 256, 0, stream>>>(ea, w_e, E, ale1, ale2);

  const int nrb = (N + 127) / 128;   // 157 row blocks
  const int mmgrid = nrb * 8;        // 1256 blocks (128 rows x 2 heads), XCD-swizzled

  // layer 1
  k_matmul<<<mmgrid, 256, 0, stream>>>(x, W1, as1, ad1, N, nrb, xp, al_s, al_d);
  k_att<<<(N + 3) / 4, 256, 0, stream>>>(al_s, al_d, ale1, row_start, eid, srcc, E, N, att);
  k_csc_z<<<(N + 3) / 4, 256, 0, stream>>>(xp, att, srow, smap, N, z);
  k_sum_z<<<(N + 15) / 16, 256, 0, stream>>>(z, row_start, b1, N, hbuf);

  // layer 2
  k_matmul<<<mmgrid, 256, 0, stream>>>(hbuf, W2, as2, ad2, N, nrb, xp, al_s, al_d);
  k_att<<<(N + 3) / 4, 256, 0, stream>>>(al_s, al_d, ale2, row_start, eid, srcc, E, N, att);
  k_csc_z<<<(N + 3) / 4, 256, 0, stream>>>(xp, att, srow, smap, N, z);
  k_sum_z<<<(N + 15) / 16, 256, 0, stream>>>(z, row_start, b2, N, (float*)d_out);
}

// Round 13
// 283.760 us; speedup vs baseline: 3.2738x; 1.0524x over previous
//
#include <hip/hip_runtime.h>

// GAT (2-layer, PyG GATConv semantics) on MI355X — src-major aggregation,
// bf16-split MFMA feature GEMM.
// N=20000 nodes, E=100000 edges (+N self-loops), D=64, H=16 heads, C=64 ch/head.
constexpr int TD  = 64;      // input feature dim
constexpr int TH  = 16;      // heads
constexpr int TC  = 64;      // channels per head
constexpr int THC = TH * TC; // 1024

typedef short bf16x8 __attribute__((ext_vector_type(8)));
typedef unsigned short u16x8 __attribute__((ext_vector_type(8)));
typedef float f32x4 __attribute__((ext_vector_type(4)));

static __device__ __forceinline__ unsigned short f2bf(float f) {  // RNE f32->bf16
  unsigned u = __float_as_uint(f);
  u += 0x7FFF + ((u >> 16) & 1);
  return (unsigned short)(u >> 16);
}
static __device__ __forceinline__ float bf2f(unsigned short h) {
  return __uint_as_float(((unsigned)h) << 16);
}

// ---------------- CSR/CSC build (once, shared by both layers) ----------------

__global__ void k_count2(const int* __restrict__ src, const int* __restrict__ dst,
                         int E, int N, int* __restrict__ degd, int* __restrict__ degs) {
  int e = blockIdx.x * blockDim.x + threadIdx.x;
  if (e >= E + N) return;
  int s, d;
  if (e < E) { s = src[e]; d = dst[e]; } else { s = d = e - E; }
  atomicAdd(&degd[d], 1);
  atomicAdd(&degs[s], 1);
}

__global__ void k_scan2(const int* __restrict__ degd, int N,
                        int* __restrict__ row_start, int* __restrict__ cursor,
                        const int* __restrict__ degs,
                        int* __restrict__ srow, int* __restrict__ scursor) {
  const int* dg = blockIdx.x ? degs : degd;
  int* rs = blockIdx.x ? srow : row_start;
  int* cu = blockIdx.x ? scursor : cursor;
  __shared__ int part[256];
  int t = threadIdx.x;
  int chunk = (N + 255) / 256;
  int lo = t * chunk, hi = min(lo + chunk, N);
  int s = 0;
  for (int i = lo; i < hi; ++i) s += dg[i];
  part[t] = s;
  __syncthreads();
  if (t == 0) {
    int run = 0;
    for (int i = 0; i < 256; ++i) { int v = part[i]; part[i] = run; run += v; }
    rs[N] = run;
  }
  __syncthreads();
  int run = part[t];
  for (int i = lo; i < hi; ++i) {
    rs[i] = run; cu[i] = run; run += dg[i];
  }
}

__global__ void k_scatter_dst(const int* __restrict__ src, const int* __restrict__ dst,
                              int E, int N, int* __restrict__ cursor,
                              int* __restrict__ eid, int* __restrict__ srcc,
                              int* __restrict__ inv) {
  int e = blockIdx.x * blockDim.x + threadIdx.x;
  if (e >= E + N) return;
  int s, d;
  if (e < E) { s = src[e]; d = dst[e]; } else { s = d = e - E; }
  int pos = atomicAdd(&cursor[d], 1);
  eid[pos] = e; srcc[pos] = s; inv[e] = pos;
}

__global__ void k_scatter_src(const int* __restrict__ src, int E, int N,
                              int* __restrict__ scursor, const int* __restrict__ inv,
                              int* __restrict__ smap) {
  int e = blockIdx.x * blockDim.x + threadIdx.x;
  if (e >= E + N) return;
  int s = (e < E) ? src[e] : (e - E);
  int j = atomicAdd(&scursor[s], 1);
  smap[j] = inv[e];
}

// ---------------- bf16-split prep ----------------

// Pack W (both layers) into B-fragment order for mfma_f32_16x16x32_bf16:
// B[k][j]: j = lane&15, k = ks*32 + (lane>>4)*8 + i.
// Flat: Wb[((layer*64 + ct)*2 + ks)*512 + lane*8 + i], ct = 16-col tile.
__global__ void k_prep_w(const float* __restrict__ W1, const float* __restrict__ W2,
                         unsigned short* __restrict__ Wbh, unsigned short* __restrict__ Wbl) {
  int t = blockIdx.x * 256 + threadIdx.x;   // t = ((layer*64+ct)*2+ks)*64+lane
  if (t >= 2 * 64 * 2 * 64) return;
  int lane = t & 63, ks = (t >> 6) & 1, ct = (t >> 7) & 63, layer = t >> 13;
  const float* W = layer ? W2 : W1;
  int col = ct * 16 + (lane & 15);
  int kb = ks * 32 + ((lane >> 4) << 3);
  u16x8 H, L;
#pragma unroll
  for (int i = 0; i < 8; ++i) {
    float v = W[(size_t)(kb + i) * THC + col];
    unsigned short hi = f2bf(v);
    H[i] = hi;
    L[i] = f2bf(v - bf2f(hi));
  }
  *(u16x8*)&Wbh[(size_t)t * 8] = H;
  *(u16x8*)&Wbl[(size_t)t * 8] = L;
}

// Split input rows (x or hbuf) into bf16 hi/lo, row-major [Npad][64]; pad rows zero.
__global__ __launch_bounds__(256) void k_prep_x(const float* __restrict__ xin, int N, int Npad,
                                                unsigned short* __restrict__ xbh,
                                                unsigned short* __restrict__ xbl) {
  int t = blockIdx.x * 256 + threadIdx.x;   // one 8-elem chunk
  if (t >= Npad * 8) return;
  int row = t >> 3, c8 = (t & 7) * 8;
  u16x8 H = {0, 0, 0, 0, 0, 0, 0, 0}, L = {0, 0, 0, 0, 0, 0, 0, 0};
  if (row < N) {
    float4 v0 = *(const float4*)&xin[(size_t)row * TD + c8];
    float4 v1 = *(const float4*)&xin[(size_t)row * TD + c8 + 4];
    float v[8] = {v0.x, v0.y, v0.z, v0.w, v1.x, v1.y, v1.z, v1.w};
#pragma unroll
    for (int i = 0; i < 8; ++i) {
      unsigned short hi = f2bf(v[i]);
      H[i] = hi;
      L[i] = f2bf(v[i] - bf2f(hi));
    }
  }
  *(u16x8*)&xbh[(size_t)row * TD + c8] = H;
  *(u16x8*)&xbl[(size_t)row * TD + c8] = L;
}

// ---------------- MFMA feature GEMM ----------------

// xp = x @ W via bf16-split (3 MFMA terms: hh + hl + lh; lo*lo ~ 2^-18, dropped).
// Block = 64 rows x 128 cols (head pair), 4 waves; wave w owns rows r0+16w..+16.
// Per wave: A frags direct from packed xb (row = lane&15, k-chunk = lane>>4);
// B frags from packed Wb (1 KB coalesced per load); 8 n-tiles x 2 ks x 3 = 48 MFMA.
// No LDS, no barriers. Fused epilogue: al_s/al_d via 16-lane shfl reduce.
// D layout (m89-verified): col = lane&15, row = (lane>>4)*4 + reg.
__global__ __launch_bounds__(256) void k_matmul_mfma(
    const unsigned short* __restrict__ xbh, const unsigned short* __restrict__ xbl,
    const unsigned short* __restrict__ Wbh, const unsigned short* __restrict__ Wbl,
    const float* __restrict__ a_src, const float* __restrict__ a_dst,
    int N, int nrb, float* __restrict__ xp,
    float* __restrict__ al_s, float* __restrict__ al_d) {
  int tid = threadIdx.x;
  // bijective XCD swizzle (measured: keeps FETCH L2-resident, R8/R9)
  int nwg = nrb * 8;
  int wg = blockIdx.x;
  int q = nwg >> 3, rm = nwg & 7;
  int xcd = wg & 7, off = wg >> 3;
  int g = (xcd < rm ? xcd * (q + 1) : rm * (q + 1) + (xcd - rm) * q) + off;
  int hp = g & 7;                    // head pair
  int rb = g >> 3;
  int r0 = rb * 64;
  int w = tid >> 6, l = tid & 63;

  int arow = r0 + w * 16 + (l & 15);
  const unsigned short* xh = xbh + (size_t)arow * TD + ((l >> 4) << 3);
  const unsigned short* xl = xbl + (size_t)arow * TD + ((l >> 4) << 3);
  bf16x8 ah0 = *(const bf16x8*)xh;
  bf16x8 ah1 = *(const bf16x8*)(xh + 32);
  bf16x8 alo0 = *(const bf16x8*)xl;
  bf16x8 alo1 = *(const bf16x8*)(xl + 32);

  f32x4 acc[8];
  int ct0 = hp * 8;
#pragma unroll
  for (int nt = 0; nt < 8; ++nt) {
    size_t base = ((size_t)(ct0 + nt) * 2) * 512 + l * 8;
    bf16x8 bh0 = *(const bf16x8*)&Wbh[base];
    bf16x8 bh1 = *(const bf16x8*)&Wbh[base + 512];
    bf16x8 bl0 = *(const bf16x8*)&Wbl[base];
    bf16x8 bl1 = *(const bf16x8*)&Wbl[base + 512];
    f32x4 a = {0.f, 0.f, 0.f, 0.f};
    a = __builtin_amdgcn_mfma_f32_16x16x32_bf16(ah0, bh0, a, 0, 0, 0);
    a = __builtin_amdgcn_mfma_f32_16x16x32_bf16(ah1, bh1, a, 0, 0, 0);
    a = __builtin_amdgcn_mfma_f32_16x16x32_bf16(ah0, bl0, a, 0, 0, 0);
    a = __builtin_amdgcn_mfma_f32_16x16x32_bf16(ah1, bl1, a, 0, 0, 0);
    a = __builtin_amdgcn_mfma_f32_16x16x32_bf16(alo0, bh0, a, 0, 0, 0);
    a = __builtin_amdgcn_mfma_f32_16x16x32_bf16(alo1, bh1, a, 0, 0, 0);
    acc[nt] = a;
  }

  int rbase = r0 + w * 16 + ((l >> 4) << 2);
  int cl = l & 15;
  // xp store: 16 lanes cover 16 consecutive cols -> 64B coalesced segments
#pragma unroll
  for (int nt = 0; nt < 8; ++nt) {
    int colg = hp * 128 + nt * 16 + cl;
#pragma unroll
    for (int r = 0; r < 4; ++r) {
      int rowg = rbase + r;
      if (rowg < N) xp[(size_t)rowg * THC + colg] = acc[nt][r];
    }
  }
  // fused al_s/al_d
#pragma unroll
  for (int hh = 0; hh < 2; ++hh) {
    int h = 2 * hp + hh;
    float as0 = a_src[h * TC + 0 * 16 + cl], as1 = a_src[h * TC + 1 * 16 + cl];
    float as2 = a_src[h * TC + 2 * 16 + cl], as3 = a_src[h * TC + 3 * 16 + cl];
    float ad0 = a_dst[h * TC + 0 * 16 + cl], ad1 = a_dst[h * TC + 1 * 16 + cl];
    float ad2 = a_dst[h * TC + 2 * 16 + cl], ad3 = a_dst[h * TC + 3 * 16 + cl];
#pragma unroll
    for (int r = 0; r < 4; ++r) {
      float ps = acc[hh * 4 + 0][r] * as0 + acc[hh * 4 + 1][r] * as1 +
                 acc[hh * 4 + 2][r] * as2 + acc[hh * 4 + 3][r] * as3;
      float pd = acc[hh * 4 + 0][r] * ad0 + acc[hh * 4 + 1][r] * ad1 +
                 acc[hh * 4 + 2][r] * ad2 + acc[hh * 4 + 3][r] * ad3;
      for (int m = 8; m >= 1; m >>= 1) {
        ps += __shfl_xor(ps, m, 16);
        pd += __shfl_xor(pd, m, 16);
      }
      int rowg = rbase + r;
      if (cl == 0 && rowg < N) { al_s[rowg * TH + h] = ps; al_d[rowg * TH + h] = pd; }
    }
  }
}

// ---------------- edge logits / attention / aggregation (measured-good) -------

// w_e for BOTH layers: w_e[layer][d][h] = sum_c We[d, h*64+c] * a_e[h,c]
__global__ void k_we2(const float* __restrict__ We1, const float* __restrict__ ae1,
                      const float* __restrict__ We2, const float* __restrict__ ae2,
                      float* __restrict__ w_e) {
  int t = blockIdx.x * blockDim.x + threadIdx.x;
  if (t >= 2 * TD * TH) return;
  int layer = t >> 10, tt = t & 1023;
  int d = tt >> 4, h = tt & 15;
  const float* We = layer ? We2 : We1;
  const float* ae = layer ? ae2 : ae1;
  float s = 0.f;
  for (int c = 0; c < TC; ++c) s += We[(size_t)d * THC + h * TC + c] * ae[h * TC + c];
  w_e[t] = s;
}

// ale[e,h] for BOTH layers (blockIdx.y = layer), real edges, coalesced over e
__global__ __launch_bounds__(256) void k_al_e2(const float* __restrict__ ea,
                                               const float* __restrict__ w_e,
                                               int E, float* __restrict__ ale1,
                                               float* __restrict__ ale2) {
  __shared__ float sea[16][64];
  __shared__ float swe[TD * TH];
  int tid = threadIdx.x;
  int e0 = blockIdx.x * 16;
  const float* we = w_e + blockIdx.y * (TD * TH);
  float* ale = blockIdx.y ? ale2 : ale1;
  for (int i = tid; i < TD * TH; i += 256) swe[i] = we[i];
  {
    int idx = tid * 4;
    int le = idx >> 6, d = idx & 63;
    int e = e0 + le;
    float4 v = make_float4(0.f, 0.f, 0.f, 0.f);
    if (e < E) v = *(const float4*)&ea[(size_t)e * TD + d];
    *(float4*)&sea[le][d] = v;
  }
  __syncthreads();
  int le = tid >> 4, h = tid & 15;
  int e = e0 + le;
  if (e >= E) return;
  float s = 0.f;
  for (int dd = 0; dd < TD; ++dd) {
    int d = (dd + le * 8) & 63;              // rotate start: conflict-free LDS banks
    s += sea[le][d] * swe[d * TH + h];
  }
  ale[(size_t)e * TH + h] = s;
}

// one WAVE per dst node, barrier/LDS-free (measured win R9): lane = h + 16*slot.
__global__ __launch_bounds__(256) void k_att(
    const float* __restrict__ al_s, const float* __restrict__ al_d,
    const float* __restrict__ ale, const int* __restrict__ row_start,
    const int* __restrict__ eid, const int* __restrict__ srcc,
    int E, int N, float* __restrict__ att) {
  int tid = threadIdx.x;
  int n = blockIdx.x * 4 + (tid >> 6);
  if (n >= N) return;
  int lane = tid & 63;
  int h = lane & 15, slot = lane >> 4;
  int beg = row_start[n], end = row_start[n + 1], deg = end - beg;
  float ald = al_d[n * TH + h];

  float a0 = 0.f, a1 = 0.f, a2 = 0.f, a3 = 0.f;
  float asum = 0.f;
  int selfp = -1;
  int cnt = 0;
  for (int p = slot; p < deg; p += 4, ++cnt) {
    int i = beg + p;
    int e = eid[i], s = srcc[i];
    float av = 0.f;
    if (e < E) { av = ale[(size_t)e * TH + h]; asum += av; }
    else selfp = p;
    float a = al_s[s * TH + h] + ald + av;
    if (cnt == 0) a0 = a; else if (cnt == 1) a1 = a;
    else if (cnt == 2) a2 = a; else if (cnt == 3) a3 = a;
  }
  asum += __shfl_xor(asum, 16);
  asum += __shfl_xor(asum, 32);
  float lale = asum / (float)max(deg - 1, 1);

  auto fin = [&](float a, int p) -> float {
    if (p == selfp) a += lale;
    return (a > 0.f) ? a : 0.2f * a;
  };
  auto raw = [&](int p) -> float {
    int i = beg + p;
    int e = eid[i], s = srcc[i];
    float av = (e < E) ? ale[(size_t)e * TH + h] : 0.f;
    return al_s[s * TH + h] + ald + av;
  };

  float mloc = -1e30f;
  cnt = 0;
  for (int p = slot; p < deg; p += 4, ++cnt) {
    float a;
    if      (cnt == 0) { a0 = fin(a0, p); a = a0; }
    else if (cnt == 1) { a1 = fin(a1, p); a = a1; }
    else if (cnt == 2) { a2 = fin(a2, p); a = a2; }
    else if (cnt == 3) { a3 = fin(a3, p); a = a3; }
    else a = fin(raw(p), p);
    mloc = fmaxf(mloc, a);
  }
  mloc = fmaxf(mloc, __shfl_xor(mloc, 16));
  mloc = fmaxf(mloc, __shfl_xor(mloc, 32));

  float dloc = 0.f;
  cnt = 0;
  for (int p = slot; p < deg; p += 4, ++cnt) {
    float a = (cnt == 0) ? a0 : (cnt == 1) ? a1 : (cnt == 2) ? a2 : (cnt == 3) ? a3
              : fin(raw(p), p);
    dloc += expf(a - mloc);
  }
  dloc += __shfl_xor(dloc, 16);
  dloc += __shfl_xor(dloc, 32);
  float dinv = 1.f / (dloc + 1e-16f);

  cnt = 0;
  for (int p = slot; p < deg; p += 4, ++cnt) {
    float a = (cnt == 0) ? a0 : (cnt == 1) ? a1 : (cnt == 2) ? a2 : (cnt == 3) ? a3
              : fin(raw(p), p);
    att[(size_t)(beg + p) * TH + h] = expf(a - mloc) * dinv;
  }
}

// src-major, LDS/barrier-free: one WAVE per src node; lane keeps 16-head xp slice.
__global__ __launch_bounds__(256) void k_csc_z(const float* __restrict__ xp,
                                               const float* __restrict__ att,
                                               const int* __restrict__ srow,
                                               const int* __restrict__ smap,
                                               int N, float* __restrict__ z) {
  int tid = threadIdx.x;
  int s = blockIdx.x * 4 + (tid >> 6);
  if (s >= N) return;
  int lane = tid & 63;
  int slot = lane >> 4, c4 = (lane & 15) * 4;
  float4 xf[16];
#pragma unroll
  for (int h = 0; h < TH; ++h)
    xf[h] = *(const float4*)&xp[(size_t)s * THC + h * 64 + c4];
  int beg = srow[s], end = srow[s + 1];
  for (int j = beg + slot; j < end; j += 4) {
    int i = smap[j];
    const float* ar = &att[(size_t)i * TH];
    float4 a0 = *(const float4*)&ar[0];
    float4 a1 = *(const float4*)&ar[4];
    float4 a2 = *(const float4*)&ar[8];
    float4 a3 = *(const float4*)&ar[12];
    float aw[16] = {a0.x, a0.y, a0.z, a0.w, a1.x, a1.y, a1.z, a1.w,
                    a2.x, a2.y, a2.z, a2.w, a3.x, a3.y, a3.z, a3.w};
    float4 acc = make_float4(0.f, 0.f, 0.f, 0.f);
#pragma unroll
    for (int hh = 0; hh < TH; ++hh) {
      acc.x += aw[hh] * xf[hh].x; acc.y += aw[hh] * xf[hh].y;
      acc.z += aw[hh] * xf[hh].z; acc.w += aw[hh] * xf[hh].w;
    }
    *(float4*)&z[(size_t)i * 64 + c4] = acc;
  }
}

// per-dst: sum contiguous z segment, head-mean + bias + relu.
__global__ __launch_bounds__(256) void k_sum_z(const float* __restrict__ z,
                                               const int* __restrict__ row_start,
                                               const float* __restrict__ bias, int N,
                                               float* __restrict__ out) {
  int tid = threadIdx.x;
  int n = blockIdx.x * 16 + (tid >> 4);
  int c4 = (tid & 15) * 4;
  if (n >= N) return;
  int beg = row_start[n], end = row_start[n + 1];
  float4 acc = make_float4(0.f, 0.f, 0.f, 0.f);
  for (int i = beg; i < end; ++i) {
    float4 v = *(const float4*)&z[(size_t)i * 64 + c4];
    acc.x += v.x; acc.y += v.y; acc.z += v.z; acc.w += v.w;
  }
  float4 b = *(const float4*)&bias[c4];
  float4 o;
  o.x = fmaxf(acc.x * (1.0f / TH) + b.x, 0.f);
  o.y = fmaxf(acc.y * (1.0f / TH) + b.y, 0.f);
  o.z = fmaxf(acc.z * (1.0f / TH) + b.z, 0.f);
  o.w = fmaxf(acc.w * (1.0f / TH) + b.w, 0.f);
  *(float4*)&out[(size_t)n * 64 + c4] = o;
}

// ---------------- launch ----------------

extern "C" void kernel_launch(void* const* d_in, const int* in_sizes, int n_in,
                              void* d_out, int out_size, void* d_ws, size_t ws_size,
                              hipStream_t stream) {
  const float* x   = (const float*)d_in[0];
  const int*   ei  = (const int*)d_in[1];
  const float* ea  = (const float*)d_in[2];
  const float* W1  = (const float*)d_in[3];
  const float* as1 = (const float*)d_in[4];
  const float* ad1 = (const float*)d_in[5];
  const float* We1 = (const float*)d_in[6];
  const float* ae1 = (const float*)d_in[7];
  const float* b1  = (const float*)d_in[8];
  const float* W2  = (const float*)d_in[9];
  const float* as2 = (const float*)d_in[10];
  const float* ad2 = (const float*)d_in[11];
  const float* We2 = (const float*)d_in[12];
  const float* ae2 = (const float*)d_in[13];
  const float* b2  = (const float*)d_in[14];

  const int N  = in_sizes[0] / TD;   // 20000
  const int E  = in_sizes[1] / 2;    // 100000
  const int EN = E + N;              // 120000 (with self-loops)
  const int* srcA = ei;
  const int* dstA = ei + E;

  char* w = (char*)d_ws;
  auto alloc = [&](size_t bytes) {
    char* p = w;
    w += (bytes + 255) & ~(size_t)255;
    return p;
  };
  int*   deg2      = (int*)alloc((size_t)2 * N * 4);      // degd | degs
  int*   degd      = deg2;
  int*   degs      = deg2 + N;
  int*   row_start = (int*)alloc((size_t)(N + 1) * 4);
  int*   srow      = (int*)alloc((size_t)(N + 1) * 4);
  int*   cursor    = (int*)alloc((size_t)N * 4);
  int*   scursor   = (int*)alloc((size_t)N * 4);
  int*   eid       = (int*)alloc((size_t)EN * 4);
  int*   srcc      = (int*)alloc((size_t)EN * 4);
  int*   inv       = (int*)alloc((size_t)EN * 4);
  int*   smap      = (int*)alloc((size_t)EN * 4);
  float* xp        = (float*)alloc((size_t)N * THC * 4);  // 82 MB
  float* al_s      = (float*)alloc((size_t)N * TH * 4);
  float* al_d      = (float*)alloc((size_t)N * TH * 4);
  float* ale1      = (float*)alloc((size_t)E * TH * 4);   // 6.4 MB
  float* ale2      = (float*)alloc((size_t)E * TH * 4);   // 6.4 MB
  float* att       = (float*)alloc((size_t)EN * TH * 4);  // 7.7 MB
  float* z         = (float*)alloc((size_t)EN * TC * 4);  // 30.7 MB
  float* w_e       = (float*)alloc((size_t)2 * TD * TH * 4);
  const int nrb  = (N + 63) / 64;    // 313 row blocks (64 rows each)
  const int Npad = nrb * 64;         // 20032
  unsigned short* xbh = (unsigned short*)alloc((size_t)Npad * TD * 2);
  unsigned short* xbl = (unsigned short*)alloc((size_t)Npad * TD * 2);
  unsigned short* Wbh = (unsigned short*)alloc((size_t)2 * 64 * 2 * 64 * 8 * 2);
  unsigned short* Wbl = (unsigned short*)alloc((size_t)2 * 64 * 2 * 64 * 8 * 2);
  float* hbuf      = (float*)ale1; // overlay: ale1 dead after k_att layer 1

  // CSR (by dst) + CSC (by src) build, shared by both layers
  hipMemsetAsync(deg2, 0, (size_t)2 * N * 4, stream);
  k_count2<<<(EN + 255) / 256, 256, 0, stream>>>(srcA, dstA, E, N, degd, degs);
  k_scan2<<<2, 256, 0, stream>>>(degd, N, row_start, cursor, degs, srow, scursor);
  k_scatter_dst<<<(EN + 255) / 256, 256, 0, stream>>>(srcA, dstA, E, N, cursor, eid, srcc, inv);
  k_scatter_src<<<(EN + 255) / 256, 256, 0, stream>>>(srcA, E, N, scursor, inv, smap);

  // W fragment-pack + edge-attention logits for BOTH layers up-front
  k_prep_w<<<(2 * 64 * 2 * 64 + 255) / 256, 256, 0, stream>>>(W1, W2, Wbh, Wbl);
  k_we2<<<8, 256, 0, stream>>>(We1, ae1, We2, ae2, w_e);
  dim3 aleg((E + 15) / 16, 2);
  k_al_e2<<<aleg, 256, 0, stream>>>(ea, w_e, E, ale1, ale2);

  const int mmgrid = nrb * 8;        // 2504 blocks (64 rows x 2 heads), XCD-swizzled
  const size_t WBL = 64 * 2 * 64 * 8;  // per-layer Wb elements

  // layer 1
  k_prep_x<<<(Npad * 8 + 255) / 256, 256, 0, stream>>>(x, N, Npad, xbh, xbl);
  k_matmul_mfma<<<mmgrid, 256, 0, stream>>>(xbh, xbl, Wbh, Wbl, as1, ad1,
                                            N, nrb, xp, al_s, al_d);
  k_att<<<(N + 3) / 4, 256, 0, stream>>>(al_s, al_d, ale1, row_start, eid, srcc, E, N, att);
  k_csc_z<<<(N + 3) / 4, 256, 0, stream>>>(xp, att, srow, smap, N, z);
  k_sum_z<<<(N + 15) / 16, 256, 0, stream>>>(z, row_start, b1, N, hbuf);

  // layer 2
  k_prep_x<<<(Npad * 8 + 255) / 256, 256, 0, stream>>>(hbuf, N, Npad, xbh, xbl);
  k_matmul_mfma<<<mmgrid, 256, 0, stream>>>(xbh, xbl, Wbh + WBL, Wbl + WBL, as2, ad2,
                                            N, nrb, xp, al_s, al_d);
  k_att<<<(N + 3) / 4, 256, 0, stream>>>(al_s, al_d, ale2, row_start, eid, srcc, E, N, att);
  k_csc_z<<<(N + 3) / 4, 256, 0, stream>>>(xp, att, srow, smap, N, z);
  k_sum_z<<<(N + 15) / 16, 256, 0, stream>>>(z, row_start, b2, N, (float*)d_out);
}

// Round 14
// 266.061 us; speedup vs baseline: 3.4915x; 1.0665x over previous
//
#include <hip/hip_runtime.h>

// GAT (2-layer, PyG GATConv semantics) on MI355X — src-major aggregation,
// bf16-split MFMA feature GEMM.
// N=20000 nodes, E=100000 edges (+N self-loops), D=64, H=16 heads, C=64 ch/head.
constexpr int TD  = 64;      // input feature dim
constexpr int TH  = 16;      // heads
constexpr int TC  = 64;      // channels per head
constexpr int THC = TH * TC; // 1024

typedef short bf16x8 __attribute__((ext_vector_type(8)));
typedef unsigned short u16x8 __attribute__((ext_vector_type(8)));
typedef float f32x4 __attribute__((ext_vector_type(4)));

static __device__ __forceinline__ unsigned short f2bf(float f) {  // RNE f32->bf16
  unsigned u = __float_as_uint(f);
  u += 0x7FFF + ((u >> 16) & 1);
  return (unsigned short)(u >> 16);
}
static __device__ __forceinline__ float bf2f(unsigned short h) {
  return __uint_as_float(((unsigned)h) << 16);
}

// ---------------- CSR/CSC build (once, shared by both layers) ----------------

__global__ void k_count2(const int* __restrict__ src, const int* __restrict__ dst,
                         int E, int N, int* __restrict__ degd, int* __restrict__ degs) {
  int e = blockIdx.x * blockDim.x + threadIdx.x;
  if (e >= E + N) return;
  int s, d;
  if (e < E) { s = src[e]; d = dst[e]; } else { s = d = e - E; }
  atomicAdd(&degd[d], 1);
  atomicAdd(&degs[s], 1);
}

// hierarchical exclusive scan, 1024 threads (R13: serial version was 48 us, #1
// kernel — latency-bound at 2 blocks; this is ~4 us). block 0: dst, block 1: src.
__global__ __launch_bounds__(1024) void k_scan2(
    const int* __restrict__ degd, int N,
    int* __restrict__ row_start, int* __restrict__ cursor,
    const int* __restrict__ degs,
    int* __restrict__ srow, int* __restrict__ scursor) {
  const int* dg = blockIdx.x ? degs : degd;
  int* rs = blockIdx.x ? srow : row_start;
  int* cu = blockIdx.x ? scursor : cursor;
  __shared__ int wsum[16];
  int t = threadIdx.x;
  int chunk = (N + 1023) / 1024;
  int lo = min(t * chunk, N), hi = min(lo + chunk, N);
  int s = 0;
  for (int i = lo; i < hi; ++i) s += dg[i];
  int lane = t & 63, wid = t >> 6;
  int v = s;                              // wave inclusive scan
  for (int d = 1; d < 64; d <<= 1) {
    int u = __shfl_up(v, d, 64);
    if (lane >= d) v += u;
  }
  if (lane == 63) wsum[wid] = v;
  __syncthreads();
  if (t < 16) {                           // scan the 16 wave totals
    int wv = wsum[t];
    for (int d = 1; d < 16; d <<= 1) {
      int u = __shfl_up(wv, d, 16);
      if (t >= d) wv += u;
    }
    wsum[t] = wv;                         // inclusive
  }
  __syncthreads();
  int waveoff = wid ? wsum[wid - 1] : 0;
  int run = waveoff + (v - s);            // exclusive prefix of this thread's chunk
  for (int i = lo; i < hi; ++i) {
    rs[i] = run; cu[i] = run; run += dg[i];
  }
  if (t == 1023) rs[N] = waveoff + v;     // grand total
}

__global__ void k_scatter_dst(const int* __restrict__ src, const int* __restrict__ dst,
                              int E, int N, int* __restrict__ cursor,
                              int* __restrict__ eid, int* __restrict__ srcc,
                              int* __restrict__ inv) {
  int e = blockIdx.x * blockDim.x + threadIdx.x;
  if (e >= E + N) return;
  int s, d;
  if (e < E) { s = src[e]; d = dst[e]; } else { s = d = e - E; }
  int pos = atomicAdd(&cursor[d], 1);
  eid[pos] = e; srcc[pos] = s; inv[e] = pos;
}

__global__ void k_scatter_src(const int* __restrict__ src, int E, int N,
                              int* __restrict__ scursor, const int* __restrict__ inv,
                              int* __restrict__ smap) {
  int e = blockIdx.x * blockDim.x + threadIdx.x;
  if (e >= E + N) return;
  int s = (e < E) ? src[e] : (e - E);
  int j = atomicAdd(&scursor[s], 1);
  smap[j] = inv[e];
}

// ---------------- bf16-split prep ----------------

// Pack W (both layers) into B-fragment order for mfma_f32_16x16x32_bf16:
// B[k][j]: j = lane&15, k = ks*32 + (lane>>4)*8 + i.
// Flat: Wb[((layer*64 + ct)*2 + ks)*512 + lane*8 + i], ct = 16-col tile.
__global__ void k_prep_w(const float* __restrict__ W1, const float* __restrict__ W2,
                         unsigned short* __restrict__ Wbh, unsigned short* __restrict__ Wbl) {
  int t = blockIdx.x * 256 + threadIdx.x;   // t = ((layer*64+ct)*2+ks)*64+lane
  if (t >= 2 * 64 * 2 * 64) return;
  int lane = t & 63, ks = (t >> 6) & 1, ct = (t >> 7) & 63, layer = t >> 13;
  const float* W = layer ? W2 : W1;
  int col = ct * 16 + (lane & 15);
  int kb = ks * 32 + ((lane >> 4) << 3);
  u16x8 H, L;
#pragma unroll
  for (int i = 0; i < 8; ++i) {
    float v = W[(size_t)(kb + i) * THC + col];
    unsigned short hi = f2bf(v);
    H[i] = hi;
    L[i] = f2bf(v - bf2f(hi));
  }
  *(u16x8*)&Wbh[(size_t)t * 8] = H;
  *(u16x8*)&Wbl[(size_t)t * 8] = L;
}

// Split input rows into bf16 hi/lo, row-major [Npad][64]; pad rows zero.
// (Only needed for layer-1 input x; layer-2 split is fused into k_sum_z.)
__global__ __launch_bounds__(256) void k_prep_x(const float* __restrict__ xin, int N, int Npad,
                                                unsigned short* __restrict__ xbh,
                                                unsigned short* __restrict__ xbl) {
  int t = blockIdx.x * 256 + threadIdx.x;   // one 8-elem chunk
  if (t >= Npad * 8) return;
  int row = t >> 3, c8 = (t & 7) * 8;
  u16x8 H = {0, 0, 0, 0, 0, 0, 0, 0}, L = {0, 0, 0, 0, 0, 0, 0, 0};
  if (row < N) {
    float4 v0 = *(const float4*)&xin[(size_t)row * TD + c8];
    float4 v1 = *(const float4*)&xin[(size_t)row * TD + c8 + 4];
    float v[8] = {v0.x, v0.y, v0.z, v0.w, v1.x, v1.y, v1.z, v1.w};
#pragma unroll
    for (int i = 0; i < 8; ++i) {
      unsigned short hi = f2bf(v[i]);
      H[i] = hi;
      L[i] = f2bf(v[i] - bf2f(hi));
    }
  }
  *(u16x8*)&xbh[(size_t)row * TD + c8] = H;
  *(u16x8*)&xbl[(size_t)row * TD + c8] = L;
}

// ---------------- MFMA feature GEMM ----------------

// xp = x @ W via bf16-split (3 MFMA terms: hh + hl + lh; lo*lo ~ 2^-18, dropped).
// Block = 64 rows x 128 cols (head pair), 4 waves; wave w owns rows r0+16w..+16.
// No LDS, no barriers. Fused epilogue: al_s/al_d via 16-lane shfl reduce.
// D layout (m89-verified): col = lane&15, row = (lane>>4)*4 + reg.
__global__ __launch_bounds__(256) void k_matmul_mfma(
    const unsigned short* __restrict__ xbh, const unsigned short* __restrict__ xbl,
    const unsigned short* __restrict__ Wbh, const unsigned short* __restrict__ Wbl,
    const float* __restrict__ a_src, const float* __restrict__ a_dst,
    int N, int nrb, float* __restrict__ xp,
    float* __restrict__ al_s, float* __restrict__ al_d) {
  int tid = threadIdx.x;
  // bijective XCD swizzle (measured: keeps FETCH L2-resident, R8/R9)
  int nwg = nrb * 8;
  int wg = blockIdx.x;
  int q = nwg >> 3, rm = nwg & 7;
  int xcd = wg & 7, off = wg >> 3;
  int g = (xcd < rm ? xcd * (q + 1) : rm * (q + 1) + (xcd - rm) * q) + off;
  int hp = g & 7;                    // head pair
  int rb = g >> 3;
  int r0 = rb * 64;
  int w = tid >> 6, l = tid & 63;

  int arow = r0 + w * 16 + (l & 15);
  const unsigned short* xh = xbh + (size_t)arow * TD + ((l >> 4) << 3);
  const unsigned short* xl = xbl + (size_t)arow * TD + ((l >> 4) << 3);
  bf16x8 ah0 = *(const bf16x8*)xh;
  bf16x8 ah1 = *(const bf16x8*)(xh + 32);
  bf16x8 alo0 = *(const bf16x8*)xl;
  bf16x8 alo1 = *(const bf16x8*)(xl + 32);

  f32x4 acc[8];
  int ct0 = hp * 8;
#pragma unroll
  for (int nt = 0; nt < 8; ++nt) {
    size_t base = ((size_t)(ct0 + nt) * 2) * 512 + l * 8;
    bf16x8 bh0 = *(const bf16x8*)&Wbh[base];
    bf16x8 bh1 = *(const bf16x8*)&Wbh[base + 512];
    bf16x8 bl0 = *(const bf16x8*)&Wbl[base];
    bf16x8 bl1 = *(const bf16x8*)&Wbl[base + 512];
    f32x4 a = {0.f, 0.f, 0.f, 0.f};
    a = __builtin_amdgcn_mfma_f32_16x16x32_bf16(ah0, bh0, a, 0, 0, 0);
    a = __builtin_amdgcn_mfma_f32_16x16x32_bf16(ah1, bh1, a, 0, 0, 0);
    a = __builtin_amdgcn_mfma_f32_16x16x32_bf16(ah0, bl0, a, 0, 0, 0);
    a = __builtin_amdgcn_mfma_f32_16x16x32_bf16(ah1, bl1, a, 0, 0, 0);
    a = __builtin_amdgcn_mfma_f32_16x16x32_bf16(alo0, bh0, a, 0, 0, 0);
    a = __builtin_amdgcn_mfma_f32_16x16x32_bf16(alo1, bh1, a, 0, 0, 0);
    acc[nt] = a;
  }

  int rbase = r0 + w * 16 + ((l >> 4) << 2);
  int cl = l & 15;
#pragma unroll
  for (int nt = 0; nt < 8; ++nt) {
    int colg = hp * 128 + nt * 16 + cl;
#pragma unroll
    for (int r = 0; r < 4; ++r) {
      int rowg = rbase + r;
      if (rowg < N) xp[(size_t)rowg * THC + colg] = acc[nt][r];
    }
  }
  // fused al_s/al_d
#pragma unroll
  for (int hh = 0; hh < 2; ++hh) {
    int h = 2 * hp + hh;
    float as0 = a_src[h * TC + 0 * 16 + cl], as1 = a_src[h * TC + 1 * 16 + cl];
    float as2 = a_src[h * TC + 2 * 16 + cl], as3 = a_src[h * TC + 3 * 16 + cl];
    float ad0 = a_dst[h * TC + 0 * 16 + cl], ad1 = a_dst[h * TC + 1 * 16 + cl];
    float ad2 = a_dst[h * TC + 2 * 16 + cl], ad3 = a_dst[h * TC + 3 * 16 + cl];
#pragma unroll
    for (int r = 0; r < 4; ++r) {
      float ps = acc[hh * 4 + 0][r] * as0 + acc[hh * 4 + 1][r] * as1 +
                 acc[hh * 4 + 2][r] * as2 + acc[hh * 4 + 3][r] * as3;
      float pd = acc[hh * 4 + 0][r] * ad0 + acc[hh * 4 + 1][r] * ad1 +
                 acc[hh * 4 + 2][r] * ad2 + acc[hh * 4 + 3][r] * ad3;
      for (int m = 8; m >= 1; m >>= 1) {
        ps += __shfl_xor(ps, m, 16);
        pd += __shfl_xor(pd, m, 16);
      }
      int rowg = rbase + r;
      if (cl == 0 && rowg < N) { al_s[rowg * TH + h] = ps; al_d[rowg * TH + h] = pd; }
    }
  }
}

// ---------------- edge logits / attention / aggregation (measured-good) -------

__global__ void k_we2(const float* __restrict__ We1, const float* __restrict__ ae1,
                      const float* __restrict__ We2, const float* __restrict__ ae2,
                      float* __restrict__ w_e) {
  int t = blockIdx.x * blockDim.x + threadIdx.x;
  if (t >= 2 * TD * TH) return;
  int layer = t >> 10, tt = t & 1023;
  int d = tt >> 4, h = tt & 15;
  const float* We = layer ? We2 : We1;
  const float* ae = layer ? ae2 : ae1;
  float s = 0.f;
  for (int c = 0; c < TC; ++c) s += We[(size_t)d * THC + h * TC + c] * ae[h * TC + c];
  w_e[t] = s;
}

__global__ __launch_bounds__(256) void k_al_e2(const float* __restrict__ ea,
                                               const float* __restrict__ w_e,
                                               int E, float* __restrict__ ale1,
                                               float* __restrict__ ale2) {
  __shared__ float sea[16][64];
  __shared__ float swe[TD * TH];
  int tid = threadIdx.x;
  int e0 = blockIdx.x * 16;
  const float* we = w_e + blockIdx.y * (TD * TH);
  float* ale = blockIdx.y ? ale2 : ale1;
  for (int i = tid; i < TD * TH; i += 256) swe[i] = we[i];
  {
    int idx = tid * 4;
    int le = idx >> 6, d = idx & 63;
    int e = e0 + le;
    float4 v = make_float4(0.f, 0.f, 0.f, 0.f);
    if (e < E) v = *(const float4*)&ea[(size_t)e * TD + d];
    *(float4*)&sea[le][d] = v;
  }
  __syncthreads();
  int le = tid >> 4, h = tid & 15;
  int e = e0 + le;
  if (e >= E) return;
  float s = 0.f;
  for (int dd = 0; dd < TD; ++dd) {
    int d = (dd + le * 8) & 63;              // rotate start: conflict-free LDS banks
    s += sea[le][d] * swe[d * TH + h];
  }
  ale[(size_t)e * TH + h] = s;
}

// one WAVE per dst node, barrier/LDS-free (measured win R9): lane = h + 16*slot.
__global__ __launch_bounds__(256) void k_att(
    const float* __restrict__ al_s, const float* __restrict__ al_d,
    const float* __restrict__ ale, const int* __restrict__ row_start,
    const int* __restrict__ eid, const int* __restrict__ srcc,
    int E, int N, float* __restrict__ att) {
  int tid = threadIdx.x;
  int n = blockIdx.x * 4 + (tid >> 6);
  if (n >= N) return;
  int lane = tid & 63;
  int h = lane & 15, slot = lane >> 4;
  int beg = row_start[n], end = row_start[n + 1], deg = end - beg;
  float ald = al_d[n * TH + h];

  float a0 = 0.f, a1 = 0.f, a2 = 0.f, a3 = 0.f;
  float asum = 0.f;
  int selfp = -1;
  int cnt = 0;
  for (int p = slot; p < deg; p += 4, ++cnt) {
    int i = beg + p;
    int e = eid[i], s = srcc[i];
    float av = 0.f;
    if (e < E) { av = ale[(size_t)e * TH + h]; asum += av; }
    else selfp = p;
    float a = al_s[s * TH + h] + ald + av;
    if (cnt == 0) a0 = a; else if (cnt == 1) a1 = a;
    else if (cnt == 2) a2 = a; else if (cnt == 3) a3 = a;
  }
  asum += __shfl_xor(asum, 16);
  asum += __shfl_xor(asum, 32);
  float lale = asum / (float)max(deg - 1, 1);

  auto fin = [&](float a, int p) -> float {
    if (p == selfp) a += lale;
    return (a > 0.f) ? a : 0.2f * a;
  };
  auto raw = [&](int p) -> float {
    int i = beg + p;
    int e = eid[i], s = srcc[i];
    float av = (e < E) ? ale[(size_t)e * TH + h] : 0.f;
    return al_s[s * TH + h] + ald + av;
  };

  float mloc = -1e30f;
  cnt = 0;
  for (int p = slot; p < deg; p += 4, ++cnt) {
    float a;
    if      (cnt == 0) { a0 = fin(a0, p); a = a0; }
    else if (cnt == 1) { a1 = fin(a1, p); a = a1; }
    else if (cnt == 2) { a2 = fin(a2, p); a = a2; }
    else if (cnt == 3) { a3 = fin(a3, p); a = a3; }
    else a = fin(raw(p), p);
    mloc = fmaxf(mloc, a);
  }
  mloc = fmaxf(mloc, __shfl_xor(mloc, 16));
  mloc = fmaxf(mloc, __shfl_xor(mloc, 32));

  float dloc = 0.f;
  cnt = 0;
  for (int p = slot; p < deg; p += 4, ++cnt) {
    float a = (cnt == 0) ? a0 : (cnt == 1) ? a1 : (cnt == 2) ? a2 : (cnt == 3) ? a3
              : fin(raw(p), p);
    dloc += expf(a - mloc);
  }
  dloc += __shfl_xor(dloc, 16);
  dloc += __shfl_xor(dloc, 32);
  float dinv = 1.f / (dloc + 1e-16f);

  cnt = 0;
  for (int p = slot; p < deg; p += 4, ++cnt) {
    float a = (cnt == 0) ? a0 : (cnt == 1) ? a1 : (cnt == 2) ? a2 : (cnt == 3) ? a3
              : fin(raw(p), p);
    att[(size_t)(beg + p) * TH + h] = expf(a - mloc) * dinv;
  }
}

// src-major, LDS/barrier-free: one WAVE per src node; lane keeps 16-head xp slice.
__global__ __launch_bounds__(256) void k_csc_z(const float* __restrict__ xp,
                                               const float* __restrict__ att,
                                               const int* __restrict__ srow,
                                               const int* __restrict__ smap,
                                               int N, float* __restrict__ z) {
  int tid = threadIdx.x;
  int s = blockIdx.x * 4 + (tid >> 6);
  if (s >= N) return;
  int lane = tid & 63;
  int slot = lane >> 4, c4 = (lane & 15) * 4;
  float4 xf[16];
#pragma unroll
  for (int h = 0; h < TH; ++h)
    xf[h] = *(const float4*)&xp[(size_t)s * THC + h * 64 + c4];
  int beg = srow[s], end = srow[s + 1];
  for (int j = beg + slot; j < end; j += 4) {
    int i = smap[j];
    const float* ar = &att[(size_t)i * TH];
    float4 a0 = *(const float4*)&ar[0];
    float4 a1 = *(const float4*)&ar[4];
    float4 a2 = *(const float4*)&ar[8];
    float4 a3 = *(const float4*)&ar[12];
    float aw[16] = {a0.x, a0.y, a0.z, a0.w, a1.x, a1.y, a1.z, a1.w,
                    a2.x, a2.y, a2.z, a2.w, a3.x, a3.y, a3.z, a3.w};
    float4 acc = make_float4(0.f, 0.f, 0.f, 0.f);
#pragma unroll
    for (int hh = 0; hh < TH; ++hh) {
      acc.x += aw[hh] * xf[hh].x; acc.y += aw[hh] * xf[hh].y;
      acc.z += aw[hh] * xf[hh].z; acc.w += aw[hh] * xf[hh].w;
    }
    *(float4*)&z[(size_t)i * 64 + c4] = acc;
  }
}

// per-dst: sum contiguous z segment, head-mean + bias + relu.
// Optionally ALSO writes the bf16 hi/lo split of the output (fuses layer-2's
// k_prep_x — saves a dispatch + 10 MB round-trip). Pad rows of obh/obl stay
// zero from layer-1's k_prep_x.
__global__ __launch_bounds__(256) void k_sum_z(const float* __restrict__ z,
                                               const int* __restrict__ row_start,
                                               const float* __restrict__ bias, int N,
                                               float* __restrict__ out,
                                               unsigned short* __restrict__ obh,
                                               unsigned short* __restrict__ obl) {
  int tid = threadIdx.x;
  int n = blockIdx.x * 16 + (tid >> 4);
  int c4 = (tid & 15) * 4;
  if (n >= N) return;
  int beg = row_start[n], end = row_start[n + 1];
  float4 acc = make_float4(0.f, 0.f, 0.f, 0.f);
  for (int i = beg; i < end; ++i) {
    float4 v = *(const float4*)&z[(size_t)i * 64 + c4];
    acc.x += v.x; acc.y += v.y; acc.z += v.z; acc.w += v.w;
  }
  float4 b = *(const float4*)&bias[c4];
  float o[4];
  o[0] = fmaxf(acc.x * (1.0f / TH) + b.x, 0.f);
  o[1] = fmaxf(acc.y * (1.0f / TH) + b.y, 0.f);
  o[2] = fmaxf(acc.z * (1.0f / TH) + b.z, 0.f);
  o[3] = fmaxf(acc.w * (1.0f / TH) + b.w, 0.f);
  if (out) *(float4*)&out[(size_t)n * 64 + c4] = make_float4(o[0], o[1], o[2], o[3]);
  if (obh) {
    unsigned H32[2], L32[2];
#pragma unroll
    for (int p = 0; p < 2; ++p) {
      unsigned short h0 = f2bf(o[2 * p]), h1 = f2bf(o[2 * p + 1]);
      unsigned short l0 = f2bf(o[2 * p] - bf2f(h0)), l1 = f2bf(o[2 * p + 1] - bf2f(h1));
      H32[p] = (unsigned)h0 | ((unsigned)h1 << 16);
      L32[p] = (unsigned)l0 | ((unsigned)l1 << 16);
    }
    *(uint2*)&obh[(size_t)n * TD + c4] = make_uint2(H32[0], H32[1]);
    *(uint2*)&obl[(size_t)n * TD + c4] = make_uint2(L32[0], L32[1]);
  }
}

// ---------------- launch ----------------

extern "C" void kernel_launch(void* const* d_in, const int* in_sizes, int n_in,
                              void* d_out, int out_size, void* d_ws, size_t ws_size,
                              hipStream_t stream) {
  const float* x   = (const float*)d_in[0];
  const int*   ei  = (const int*)d_in[1];
  const float* ea  = (const float*)d_in[2];
  const float* W1  = (const float*)d_in[3];
  const float* as1 = (const float*)d_in[4];
  const float* ad1 = (const float*)d_in[5];
  const float* We1 = (const float*)d_in[6];
  const float* ae1 = (const float*)d_in[7];
  const float* b1  = (const float*)d_in[8];
  const float* W2  = (const float*)d_in[9];
  const float* as2 = (const float*)d_in[10];
  const float* ad2 = (const float*)d_in[11];
  const float* We2 = (const float*)d_in[12];
  const float* ae2 = (const float*)d_in[13];
  const float* b2  = (const float*)d_in[14];

  const int N  = in_sizes[0] / TD;   // 20000
  const int E  = in_sizes[1] / 2;    // 100000
  const int EN = E + N;              // 120000 (with self-loops)
  const int* srcA = ei;
  const int* dstA = ei + E;

  char* w = (char*)d_ws;
  auto alloc = [&](size_t bytes) {
    char* p = w;
    w += (bytes + 255) & ~(size_t)255;
    return p;
  };
  int*   deg2      = (int*)alloc((size_t)2 * N * 4);      // degd | degs
  int*   degd      = deg2;
  int*   degs      = deg2 + N;
  int*   row_start = (int*)alloc((size_t)(N + 1) * 4);
  int*   srow      = (int*)alloc((size_t)(N + 1) * 4);
  int*   cursor    = (int*)alloc((size_t)N * 4);
  int*   scursor   = (int*)alloc((size_t)N * 4);
  int*   eid       = (int*)alloc((size_t)EN * 4);
  int*   srcc      = (int*)alloc((size_t)EN * 4);
  int*   inv       = (int*)alloc((size_t)EN * 4);
  int*   smap      = (int*)alloc((size_t)EN * 4);
  float* xp        = (float*)alloc((size_t)N * THC * 4);  // 82 MB
  float* al_s      = (float*)alloc((size_t)N * TH * 4);
  float* al_d      = (float*)alloc((size_t)N * TH * 4);
  float* ale1      = (float*)alloc((size_t)E * TH * 4);   // 6.4 MB
  float* ale2      = (float*)alloc((size_t)E * TH * 4);   // 6.4 MB
  float* att       = (float*)alloc((size_t)EN * TH * 4);  // 7.7 MB
  float* z         = (float*)alloc((size_t)EN * TC * 4);  // 30.7 MB
  float* w_e       = (float*)alloc((size_t)2 * TD * TH * 4);
  const int nrb  = (N + 63) / 64;    // 313 row blocks (64 rows each)
  const int Npad = nrb * 64;         // 20032
  unsigned short* xbh = (unsigned short*)alloc((size_t)Npad * TD * 2);
  unsigned short* xbl = (unsigned short*)alloc((size_t)Npad * TD * 2);
  unsigned short* Wbh = (unsigned short*)alloc((size_t)2 * 64 * 2 * 64 * 8 * 2);
  unsigned short* Wbl = (unsigned short*)alloc((size_t)2 * 64 * 2 * 64 * 8 * 2);

  // CSR (by dst) + CSC (by src) build, shared by both layers
  hipMemsetAsync(deg2, 0, (size_t)2 * N * 4, stream);
  k_count2<<<(EN + 255) / 256, 256, 0, stream>>>(srcA, dstA, E, N, degd, degs);
  k_scan2<<<2, 1024, 0, stream>>>(degd, N, row_start, cursor, degs, srow, scursor);
  k_scatter_dst<<<(EN + 255) / 256, 256, 0, stream>>>(srcA, dstA, E, N, cursor, eid, srcc, inv);
  k_scatter_src<<<(EN + 255) / 256, 256, 0, stream>>>(srcA, E, N, scursor, inv, smap);

  // W fragment-pack + edge-attention logits for BOTH layers up-front
  k_prep_w<<<(2 * 64 * 2 * 64 + 255) / 256, 256, 0, stream>>>(W1, W2, Wbh, Wbl);
  k_we2<<<8, 256, 0, stream>>>(We1, ae1, We2, ae2, w_e);
  dim3 aleg((E + 15) / 16, 2);
  k_al_e2<<<aleg, 256, 0, stream>>>(ea, w_e, E, ale1, ale2);

  const int mmgrid = nrb * 8;        // 2504 blocks (64 rows x 2 heads), XCD-swizzled
  const size_t WBL = 64 * 2 * 64 * 8;  // per-layer Wb elements

  // layer 1 (k_sum_z writes the bf16 split of h directly -> no layer-2 prep)
  k_prep_x<<<(Npad * 8 + 255) / 256, 256, 0, stream>>>(x, N, Npad, xbh, xbl);
  k_matmul_mfma<<<mmgrid, 256, 0, stream>>>(xbh, xbl, Wbh, Wbl, as1, ad1,
                                            N, nrb, xp, al_s, al_d);
  k_att<<<(N + 3) / 4, 256, 0, stream>>>(al_s, al_d, ale1, row_start, eid, srcc, E, N, att);
  k_csc_z<<<(N + 3) / 4, 256, 0, stream>>>(xp, att, srow, smap, N, z);
  k_sum_z<<<(N + 15) / 16, 256, 0, stream>>>(z, row_start, b1, N, nullptr, xbh, xbl);

  // layer 2
  k_matmul_mfma<<<mmgrid, 256, 0, stream>>>(xbh, xbl, Wbh + WBL, Wbl + WBL, as2, ad2,
                                            N, nrb, xp, al_s, al_d);
  k_att<<<(N + 3) / 4, 256, 0, stream>>>(al_s, al_d, ale2, row_start, eid, srcc, E, N, att);
  k_csc_z<<<(N + 3) / 4, 256, 0, stream>>>(xp, att, srow, smap, N, z);
  k_sum_z<<<(N + 15) / 16, 256, 0, stream>>>(z, row_start, b2, N, (float*)d_out, nullptr, nullptr);
}

// Round 15
// 240.920 us; speedup vs baseline: 3.8559x; 1.1044x over previous
//
#include <hip/hip_runtime.h>

// GAT (2-layer, PyG GATConv semantics) on MI355X — src-major aggregation,
// bf16-split MFMA for BOTH the feature GEMM and the edge-logit GEMM.
// N=20000 nodes, E=100000 edges (+N self-loops), D=64, H=16 heads, C=64 ch/head.
constexpr int TD  = 64;      // input feature dim
constexpr int TH  = 16;      // heads
constexpr int TC  = 64;      // channels per head
constexpr int THC = TH * TC; // 1024

typedef short bf16x8 __attribute__((ext_vector_type(8)));
typedef unsigned short u16x8 __attribute__((ext_vector_type(8)));
typedef float f32x4 __attribute__((ext_vector_type(4)));

static __device__ __forceinline__ unsigned short f2bf(float f) {  // RNE f32->bf16
  unsigned u = __float_as_uint(f);
  u += 0x7FFF + ((u >> 16) & 1);
  return (unsigned short)(u >> 16);
}
static __device__ __forceinline__ float bf2f(unsigned short h) {
  return __uint_as_float(((unsigned)h) << 16);
}

// ---------------- CSR/CSC build (once, shared by both layers) ----------------

__global__ void k_count2(const int* __restrict__ src, const int* __restrict__ dst,
                         int E, int N, int* __restrict__ degd, int* __restrict__ degs) {
  int e = blockIdx.x * blockDim.x + threadIdx.x;
  if (e >= E + N) return;
  int s, d;
  if (e < E) { s = src[e]; d = dst[e]; } else { s = d = e - E; }
  atomicAdd(&degd[d], 1);
  atomicAdd(&degs[s], 1);
}

// hierarchical exclusive scan, 1024 threads (R13: serial version was 48 us ->
// R14: out of top-5). block 0: dst, block 1: src.
__global__ __launch_bounds__(1024) void k_scan2(
    const int* __restrict__ degd, int N,
    int* __restrict__ row_start, int* __restrict__ cursor,
    const int* __restrict__ degs,
    int* __restrict__ srow, int* __restrict__ scursor) {
  const int* dg = blockIdx.x ? degs : degd;
  int* rs = blockIdx.x ? srow : row_start;
  int* cu = blockIdx.x ? scursor : cursor;
  __shared__ int wsum[16];
  int t = threadIdx.x;
  int chunk = (N + 1023) / 1024;
  int lo = min(t * chunk, N), hi = min(lo + chunk, N);
  int s = 0;
  for (int i = lo; i < hi; ++i) s += dg[i];
  int lane = t & 63, wid = t >> 6;
  int v = s;                              // wave inclusive scan
  for (int d = 1; d < 64; d <<= 1) {
    int u = __shfl_up(v, d, 64);
    if (lane >= d) v += u;
  }
  if (lane == 63) wsum[wid] = v;
  __syncthreads();
  if (t < 16) {                           // scan the 16 wave totals
    int wv = wsum[t];
    for (int d = 1; d < 16; d <<= 1) {
      int u = __shfl_up(wv, d, 16);
      if (t >= d) wv += u;
    }
    wsum[t] = wv;                         // inclusive
  }
  __syncthreads();
  int waveoff = wid ? wsum[wid - 1] : 0;
  int run = waveoff + (v - s);            // exclusive prefix of this thread's chunk
  for (int i = lo; i < hi; ++i) {
    rs[i] = run; cu[i] = run; run += dg[i];
  }
  if (t == 1023) rs[N] = waveoff + v;     // grand total
}

__global__ void k_scatter_dst(const int* __restrict__ src, const int* __restrict__ dst,
                              int E, int N, int* __restrict__ cursor,
                              int* __restrict__ eid, int* __restrict__ srcc,
                              int* __restrict__ inv) {
  int e = blockIdx.x * blockDim.x + threadIdx.x;
  if (e >= E + N) return;
  int s, d;
  if (e < E) { s = src[e]; d = dst[e]; } else { s = d = e - E; }
  int pos = atomicAdd(&cursor[d], 1);
  eid[pos] = e; srcc[pos] = s; inv[e] = pos;
}

__global__ void k_scatter_src(const int* __restrict__ src, int E, int N,
                              int* __restrict__ scursor, const int* __restrict__ inv,
                              int* __restrict__ smap) {
  int e = blockIdx.x * blockDim.x + threadIdx.x;
  if (e >= E + N) return;
  int s = (e < E) ? src[e] : (e - E);
  int j = atomicAdd(&scursor[s], 1);
  smap[j] = inv[e];
}

// ---------------- bf16-split prep ----------------

// Pack W (both layers) into B-fragment order for mfma_f32_16x16x32_bf16:
// B[k][j]: j = lane&15, k = ks*32 + (lane>>4)*8 + i.
// Flat: Wb[((layer*64 + ct)*2 + ks)*512 + lane*8 + i], ct = 16-col tile.
__global__ void k_prep_w(const float* __restrict__ W1, const float* __restrict__ W2,
                         unsigned short* __restrict__ Wbh, unsigned short* __restrict__ Wbl) {
  int t = blockIdx.x * 256 + threadIdx.x;   // t = ((layer*64+ct)*2+ks)*64+lane
  if (t >= 2 * 64 * 2 * 64) return;
  int lane = t & 63, ks = (t >> 6) & 1, ct = (t >> 7) & 63, layer = t >> 13;
  const float* W = layer ? W2 : W1;
  int col = ct * 16 + (lane & 15);
  int kb = ks * 32 + ((lane >> 4) << 3);
  u16x8 H, L;
#pragma unroll
  for (int i = 0; i < 8; ++i) {
    float v = W[(size_t)(kb + i) * THC + col];
    unsigned short hi = f2bf(v);
    H[i] = hi;
    L[i] = f2bf(v - bf2f(hi));
  }
  *(u16x8*)&Wbh[(size_t)t * 8] = H;
  *(u16x8*)&Wbl[(size_t)t * 8] = L;
}

// Split input rows into bf16 hi/lo, row-major [Npad][64]; pad rows zero.
// (Only needed for layer-1 input x; layer-2 split is fused into k_sum_z.)
__global__ __launch_bounds__(256) void k_prep_x(const float* __restrict__ xin, int N, int Npad,
                                                unsigned short* __restrict__ xbh,
                                                unsigned short* __restrict__ xbl) {
  int t = blockIdx.x * 256 + threadIdx.x;   // one 8-elem chunk
  if (t >= Npad * 8) return;
  int row = t >> 3, c8 = (t & 7) * 8;
  u16x8 H = {0, 0, 0, 0, 0, 0, 0, 0}, L = {0, 0, 0, 0, 0, 0, 0, 0};
  if (row < N) {
    float4 v0 = *(const float4*)&xin[(size_t)row * TD + c8];
    float4 v1 = *(const float4*)&xin[(size_t)row * TD + c8 + 4];
    float v[8] = {v0.x, v0.y, v0.z, v0.w, v1.x, v1.y, v1.z, v1.w};
#pragma unroll
    for (int i = 0; i < 8; ++i) {
      unsigned short hi = f2bf(v[i]);
      H[i] = hi;
      L[i] = f2bf(v[i] - bf2f(hi));
    }
  }
  *(u16x8*)&xbh[(size_t)row * TD + c8] = H;
  *(u16x8*)&xbl[(size_t)row * TD + c8] = L;
}

// ---------------- MFMA feature GEMM ----------------

// xp = x @ W via bf16-split (3 MFMA terms: hh + hl + lh; lo*lo ~ 2^-18, dropped).
// Block = 64 rows x 128 cols (head pair), 4 waves; wave w owns rows r0+16w..+16.
// No LDS, no barriers. Fused epilogue: al_s/al_d via 16-lane shfl reduce.
// D layout (m89-verified): col = lane&15, row = (lane>>4)*4 + reg.
__global__ __launch_bounds__(256) void k_matmul_mfma(
    const unsigned short* __restrict__ xbh, const unsigned short* __restrict__ xbl,
    const unsigned short* __restrict__ Wbh, const unsigned short* __restrict__ Wbl,
    const float* __restrict__ a_src, const float* __restrict__ a_dst,
    int N, int nrb, float* __restrict__ xp,
    float* __restrict__ al_s, float* __restrict__ al_d) {
  int tid = threadIdx.x;
  // bijective XCD swizzle (measured: keeps FETCH L2-resident, R8/R9)
  int nwg = nrb * 8;
  int wg = blockIdx.x;
  int q = nwg >> 3, rm = nwg & 7;
  int xcd = wg & 7, off = wg >> 3;
  int g = (xcd < rm ? xcd * (q + 1) : rm * (q + 1) + (xcd - rm) * q) + off;
  int hp = g & 7;                    // head pair
  int rb = g >> 3;
  int r0 = rb * 64;
  int w = tid >> 6, l = tid & 63;

  int arow = r0 + w * 16 + (l & 15);
  const unsigned short* xh = xbh + (size_t)arow * TD + ((l >> 4) << 3);
  const unsigned short* xl = xbl + (size_t)arow * TD + ((l >> 4) << 3);
  bf16x8 ah0 = *(const bf16x8*)xh;
  bf16x8 ah1 = *(const bf16x8*)(xh + 32);
  bf16x8 alo0 = *(const bf16x8*)xl;
  bf16x8 alo1 = *(const bf16x8*)(xl + 32);

  f32x4 acc[8];
  int ct0 = hp * 8;
#pragma unroll
  for (int nt = 0; nt < 8; ++nt) {
    size_t base = ((size_t)(ct0 + nt) * 2) * 512 + l * 8;
    bf16x8 bh0 = *(const bf16x8*)&Wbh[base];
    bf16x8 bh1 = *(const bf16x8*)&Wbh[base + 512];
    bf16x8 bl0 = *(const bf16x8*)&Wbl[base];
    bf16x8 bl1 = *(const bf16x8*)&Wbl[base + 512];
    f32x4 a = {0.f, 0.f, 0.f, 0.f};
    a = __builtin_amdgcn_mfma_f32_16x16x32_bf16(ah0, bh0, a, 0, 0, 0);
    a = __builtin_amdgcn_mfma_f32_16x16x32_bf16(ah1, bh1, a, 0, 0, 0);
    a = __builtin_amdgcn_mfma_f32_16x16x32_bf16(ah0, bl0, a, 0, 0, 0);
    a = __builtin_amdgcn_mfma_f32_16x16x32_bf16(ah1, bl1, a, 0, 0, 0);
    a = __builtin_amdgcn_mfma_f32_16x16x32_bf16(alo0, bh0, a, 0, 0, 0);
    a = __builtin_amdgcn_mfma_f32_16x16x32_bf16(alo1, bh1, a, 0, 0, 0);
    acc[nt] = a;
  }

  int rbase = r0 + w * 16 + ((l >> 4) << 2);
  int cl = l & 15;
#pragma unroll
  for (int nt = 0; nt < 8; ++nt) {
    int colg = hp * 128 + nt * 16 + cl;
#pragma unroll
    for (int r = 0; r < 4; ++r) {
      int rowg = rbase + r;
      if (rowg < N) xp[(size_t)rowg * THC + colg] = acc[nt][r];
    }
  }
  // fused al_s/al_d
#pragma unroll
  for (int hh = 0; hh < 2; ++hh) {
    int h = 2 * hp + hh;
    float as0 = a_src[h * TC + 0 * 16 + cl], as1 = a_src[h * TC + 1 * 16 + cl];
    float as2 = a_src[h * TC + 2 * 16 + cl], as3 = a_src[h * TC + 3 * 16 + cl];
    float ad0 = a_dst[h * TC + 0 * 16 + cl], ad1 = a_dst[h * TC + 1 * 16 + cl];
    float ad2 = a_dst[h * TC + 2 * 16 + cl], ad3 = a_dst[h * TC + 3 * 16 + cl];
#pragma unroll
    for (int r = 0; r < 4; ++r) {
      float ps = acc[hh * 4 + 0][r] * as0 + acc[hh * 4 + 1][r] * as1 +
                 acc[hh * 4 + 2][r] * as2 + acc[hh * 4 + 3][r] * as3;
      float pd = acc[hh * 4 + 0][r] * ad0 + acc[hh * 4 + 1][r] * ad1 +
                 acc[hh * 4 + 2][r] * ad2 + acc[hh * 4 + 3][r] * ad3;
      for (int m = 8; m >= 1; m >>= 1) {
        ps += __shfl_xor(ps, m, 16);
        pd += __shfl_xor(pd, m, 16);
      }
      int rowg = rbase + r;
      if (cl == 0 && rowg < N) { al_s[rowg * TH + h] = ps; al_d[rowg * TH + h] = pd; }
    }
  }
}

// ---------------- edge-logit GEMM (MFMA) ----------------

// w_e for BOTH layers: w_e[layer][d][h] = sum_c We[d, h*64+c] * a_e[h,c]
__global__ void k_we2(const float* __restrict__ We1, const float* __restrict__ ae1,
                      const float* __restrict__ We2, const float* __restrict__ ae2,
                      float* __restrict__ w_e) {
  int t = blockIdx.x * blockDim.x + threadIdx.x;
  if (t >= 2 * TD * TH) return;
  int layer = t >> 10, tt = t & 1023;
  int d = tt >> 4, h = tt & 15;
  const float* We = layer ? We2 : We1;
  const float* ae = layer ? ae2 : ae1;
  float s = 0.f;
  for (int c = 0; c < TC; ++c) s += We[(size_t)d * THC + h * TC + c] * ae[h * TC + c];
  w_e[t] = s;
}

// pack w_e into B-fragment order (bf16 hi/lo): Web[(layer*2+ks)*512 + lane*8 + i],
// col j = lane&15 = head, k = ks*32 + (lane>>4)*8 + i = d.
__global__ void k_pack_we(const float* __restrict__ w_e,
                          unsigned short* __restrict__ Webh,
                          unsigned short* __restrict__ Webl) {
  int t = threadIdx.x;               // 256 threads, 1 block
  int lane = t & 63, ks = (t >> 6) & 1, layer = t >> 7;
  int h = lane & 15;
  int kb = ks * 32 + ((lane >> 4) << 3);
  u16x8 H, L;
#pragma unroll
  for (int i = 0; i < 8; ++i) {
    float v = w_e[layer * (TD * TH) + (kb + i) * TH + h];
    unsigned short hi = f2bf(v);
    H[i] = hi;
    L[i] = f2bf(v - bf2f(hi));
  }
  *(u16x8*)&Webh[(size_t)t * 8] = H;
  *(u16x8*)&Webl[(size_t)t * 8] = L;
}

// ale[e,h] for BOTH layers in one MFMA pass: [E,64] @ [64,16] x 2 layers.
// Wave handles 16 edges; A loaded fp32 from ea, bf16-split in registers
// (same verified layout as k_matmul_mfma); 12 MFMA/wave; no LDS/barriers.
// R14: LDS version was 44.8 us with 6.4M bank conflicts; this is BW-bound ~7 us.
__global__ __launch_bounds__(256) void k_al_e_mfma(
    const float* __restrict__ ea,
    const unsigned short* __restrict__ Webh, const unsigned short* __restrict__ Webl,
    int E, float* __restrict__ ale1, float* __restrict__ ale2) {
  int tid = threadIdx.x;
  int w = tid >> 6, l = tid & 63;
  int e0 = blockIdx.x * 64 + w * 16;
  int arow = e0 + (l & 15);
  int koff = (l >> 4) << 3;
  float a0[8], a1[8];
  if (arow < E) {
    float4 v0 = *(const float4*)&ea[(size_t)arow * TD + koff];
    float4 v1 = *(const float4*)&ea[(size_t)arow * TD + koff + 4];
    float4 v2 = *(const float4*)&ea[(size_t)arow * TD + 32 + koff];
    float4 v3 = *(const float4*)&ea[(size_t)arow * TD + 32 + koff + 4];
    a0[0] = v0.x; a0[1] = v0.y; a0[2] = v0.z; a0[3] = v0.w;
    a0[4] = v1.x; a0[5] = v1.y; a0[6] = v1.z; a0[7] = v1.w;
    a1[0] = v2.x; a1[1] = v2.y; a1[2] = v2.z; a1[3] = v2.w;
    a1[4] = v3.x; a1[5] = v3.y; a1[6] = v3.z; a1[7] = v3.w;
  } else {
#pragma unroll
    for (int i = 0; i < 8; ++i) { a0[i] = 0.f; a1[i] = 0.f; }
  }
  bf16x8 ah0, alo0, ah1, alo1;
#pragma unroll
  for (int i = 0; i < 8; ++i) {
    unsigned short h0 = f2bf(a0[i]);
    ah0[i] = (short)h0; alo0[i] = (short)f2bf(a0[i] - bf2f(h0));
    unsigned short h1 = f2bf(a1[i]);
    ah1[i] = (short)h1; alo1[i] = (short)f2bf(a1[i] - bf2f(h1));
  }

  f32x4 acc0 = {0.f, 0.f, 0.f, 0.f}, acc1 = {0.f, 0.f, 0.f, 0.f};
#pragma unroll
  for (int ks = 0; ks < 2; ++ks) {
    bf16x8 ah = ks ? ah1 : ah0;
    bf16x8 alo = ks ? alo1 : alo0;
    size_t b0 = (size_t)ks * 512 + l * 8;          // layer 0
    size_t b1 = (size_t)(2 + ks) * 512 + l * 8;    // layer 1
    bf16x8 bh_0 = *(const bf16x8*)&Webh[b0];
    bf16x8 bl_0 = *(const bf16x8*)&Webl[b0];
    bf16x8 bh_1 = *(const bf16x8*)&Webh[b1];
    bf16x8 bl_1 = *(const bf16x8*)&Webl[b1];
    acc0 = __builtin_amdgcn_mfma_f32_16x16x32_bf16(ah, bh_0, acc0, 0, 0, 0);
    acc0 = __builtin_amdgcn_mfma_f32_16x16x32_bf16(ah, bl_0, acc0, 0, 0, 0);
    acc0 = __builtin_amdgcn_mfma_f32_16x16x32_bf16(alo, bh_0, acc0, 0, 0, 0);
    acc1 = __builtin_amdgcn_mfma_f32_16x16x32_bf16(ah, bh_1, acc1, 0, 0, 0);
    acc1 = __builtin_amdgcn_mfma_f32_16x16x32_bf16(ah, bl_1, acc1, 0, 0, 0);
    acc1 = __builtin_amdgcn_mfma_f32_16x16x32_bf16(alo, bh_1, acc1, 0, 0, 0);
  }

  int rbase = e0 + ((l >> 4) << 2);
  int h = l & 15;
#pragma unroll
  for (int r = 0; r < 4; ++r) {
    int e = rbase + r;
    if (e < E) {
      ale1[(size_t)e * TH + h] = acc0[r];
      ale2[(size_t)e * TH + h] = acc1[r];
    }
  }
}

// ---------------- attention / aggregation (measured-good) -------

// one WAVE per dst node, barrier/LDS-free (measured win R9): lane = h + 16*slot.
__global__ __launch_bounds__(256) void k_att(
    const float* __restrict__ al_s, const float* __restrict__ al_d,
    const float* __restrict__ ale, const int* __restrict__ row_start,
    const int* __restrict__ eid, const int* __restrict__ srcc,
    int E, int N, float* __restrict__ att) {
  int tid = threadIdx.x;
  int n = blockIdx.x * 4 + (tid >> 6);
  if (n >= N) return;
  int lane = tid & 63;
  int h = lane & 15, slot = lane >> 4;
  int beg = row_start[n], end = row_start[n + 1], deg = end - beg;
  float ald = al_d[n * TH + h];

  float a0 = 0.f, a1 = 0.f, a2 = 0.f, a3 = 0.f;
  float asum = 0.f;
  int selfp = -1;
  int cnt = 0;
  for (int p = slot; p < deg; p += 4, ++cnt) {
    int i = beg + p;
    int e = eid[i], s = srcc[i];
    float av = 0.f;
    if (e < E) { av = ale[(size_t)e * TH + h]; asum += av; }
    else selfp = p;
    float a = al_s[s * TH + h] + ald + av;
    if (cnt == 0) a0 = a; else if (cnt == 1) a1 = a;
    else if (cnt == 2) a2 = a; else if (cnt == 3) a3 = a;
  }
  asum += __shfl_xor(asum, 16);
  asum += __shfl_xor(asum, 32);
  float lale = asum / (float)max(deg - 1, 1);

  auto fin = [&](float a, int p) -> float {
    if (p == selfp) a += lale;
    return (a > 0.f) ? a : 0.2f * a;
  };
  auto raw = [&](int p) -> float {
    int i = beg + p;
    int e = eid[i], s = srcc[i];
    float av = (e < E) ? ale[(size_t)e * TH + h] : 0.f;
    return al_s[s * TH + h] + ald + av;
  };

  float mloc = -1e30f;
  cnt = 0;
  for (int p = slot; p < deg; p += 4, ++cnt) {
    float a;
    if      (cnt == 0) { a0 = fin(a0, p); a = a0; }
    else if (cnt == 1) { a1 = fin(a1, p); a = a1; }
    else if (cnt == 2) { a2 = fin(a2, p); a = a2; }
    else if (cnt == 3) { a3 = fin(a3, p); a = a3; }
    else a = fin(raw(p), p);
    mloc = fmaxf(mloc, a);
  }
  mloc = fmaxf(mloc, __shfl_xor(mloc, 16));
  mloc = fmaxf(mloc, __shfl_xor(mloc, 32));

  float dloc = 0.f;
  cnt = 0;
  for (int p = slot; p < deg; p += 4, ++cnt) {
    float a = (cnt == 0) ? a0 : (cnt == 1) ? a1 : (cnt == 2) ? a2 : (cnt == 3) ? a3
              : fin(raw(p), p);
    dloc += expf(a - mloc);
  }
  dloc += __shfl_xor(dloc, 16);
  dloc += __shfl_xor(dloc, 32);
  float dinv = 1.f / (dloc + 1e-16f);

  cnt = 0;
  for (int p = slot; p < deg; p += 4, ++cnt) {
    float a = (cnt == 0) ? a0 : (cnt == 1) ? a1 : (cnt == 2) ? a2 : (cnt == 3) ? a3
              : fin(raw(p), p);
    att[(size_t)(beg + p) * TH + h] = expf(a - mloc) * dinv;
  }
}

// src-major, LDS/barrier-free: one WAVE per src node; lane keeps 16-head xp slice.
__global__ __launch_bounds__(256) void k_csc_z(const float* __restrict__ xp,
                                               const float* __restrict__ att,
                                               const int* __restrict__ srow,
                                               const int* __restrict__ smap,
                                               int N, float* __restrict__ z) {
  int tid = threadIdx.x;
  int s = blockIdx.x * 4 + (tid >> 6);
  if (s >= N) return;
  int lane = tid & 63;
  int slot = lane >> 4, c4 = (lane & 15) * 4;
  float4 xf[16];
#pragma unroll
  for (int h = 0; h < TH; ++h)
    xf[h] = *(const float4*)&xp[(size_t)s * THC + h * 64 + c4];
  int beg = srow[s], end = srow[s + 1];
  for (int j = beg + slot; j < end; j += 4) {
    int i = smap[j];
    const float* ar = &att[(size_t)i * TH];
    float4 a0 = *(const float4*)&ar[0];
    float4 a1 = *(const float4*)&ar[4];
    float4 a2 = *(const float4*)&ar[8];
    float4 a3 = *(const float4*)&ar[12];
    float aw[16] = {a0.x, a0.y, a0.z, a0.w, a1.x, a1.y, a1.z, a1.w,
                    a2.x, a2.y, a2.z, a2.w, a3.x, a3.y, a3.z, a3.w};
    float4 acc = make_float4(0.f, 0.f, 0.f, 0.f);
#pragma unroll
    for (int hh = 0; hh < TH; ++hh) {
      acc.x += aw[hh] * xf[hh].x; acc.y += aw[hh] * xf[hh].y;
      acc.z += aw[hh] * xf[hh].z; acc.w += aw[hh] * xf[hh].w;
    }
    *(float4*)&z[(size_t)i * 64 + c4] = acc;
  }
}

// per-dst: sum contiguous z segment, head-mean + bias + relu.
// Optionally ALSO writes the bf16 hi/lo split of the output (fuses layer-2's
// k_prep_x). Pad rows of obh/obl stay zero from layer-1's k_prep_x.
__global__ __launch_bounds__(256) void k_sum_z(const float* __restrict__ z,
                                               const int* __restrict__ row_start,
                                               const float* __restrict__ bias, int N,
                                               float* __restrict__ out,
                                               unsigned short* __restrict__ obh,
                                               unsigned short* __restrict__ obl) {
  int tid = threadIdx.x;
  int n = blockIdx.x * 16 + (tid >> 4);
  int c4 = (tid & 15) * 4;
  if (n >= N) return;
  int beg = row_start[n], end = row_start[n + 1];
  float4 acc = make_float4(0.f, 0.f, 0.f, 0.f);
  for (int i = beg; i < end; ++i) {
    float4 v = *(const float4*)&z[(size_t)i * 64 + c4];
    acc.x += v.x; acc.y += v.y; acc.z += v.z; acc.w += v.w;
  }
  float4 b = *(const float4*)&bias[c4];
  float o[4];
  o[0] = fmaxf(acc.x * (1.0f / TH) + b.x, 0.f);
  o[1] = fmaxf(acc.y * (1.0f / TH) + b.y, 0.f);
  o[2] = fmaxf(acc.z * (1.0f / TH) + b.z, 0.f);
  o[3] = fmaxf(acc.w * (1.0f / TH) + b.w, 0.f);
  if (out) *(float4*)&out[(size_t)n * 64 + c4] = make_float4(o[0], o[1], o[2], o[3]);
  if (obh) {
    unsigned H32[2], L32[2];
#pragma unroll
    for (int p = 0; p < 2; ++p) {
      unsigned short h0 = f2bf(o[2 * p]), h1 = f2bf(o[2 * p + 1]);
      unsigned short l0 = f2bf(o[2 * p] - bf2f(h0)), l1 = f2bf(o[2 * p + 1] - bf2f(h1));
      H32[p] = (unsigned)h0 | ((unsigned)h1 << 16);
      L32[p] = (unsigned)l0 | ((unsigned)l1 << 16);
    }
    *(uint2*)&obh[(size_t)n * TD + c4] = make_uint2(H32[0], H32[1]);
    *(uint2*)&obl[(size_t)n * TD + c4] = make_uint2(L32[0], L32[1]);
  }
}

// ---------------- launch ----------------

extern "C" void kernel_launch(void* const* d_in, const int* in_sizes, int n_in,
                              void* d_out, int out_size, void* d_ws, size_t ws_size,
                              hipStream_t stream) {
  const float* x   = (const float*)d_in[0];
  const int*   ei  = (const int*)d_in[1];
  const float* ea  = (const float*)d_in[2];
  const float* W1  = (const float*)d_in[3];
  const float* as1 = (const float*)d_in[4];
  const float* ad1 = (const float*)d_in[5];
  const float* We1 = (const float*)d_in[6];
  const float* ae1 = (const float*)d_in[7];
  const float* b1  = (const float*)d_in[8];
  const float* W2  = (const float*)d_in[9];
  const float* as2 = (const float*)d_in[10];
  const float* ad2 = (const float*)d_in[11];
  const float* We2 = (const float*)d_in[12];
  const float* ae2 = (const float*)d_in[13];
  const float* b2  = (const float*)d_in[14];

  const int N  = in_sizes[0] / TD;   // 20000
  const int E  = in_sizes[1] / 2;    // 100000
  const int EN = E + N;              // 120000 (with self-loops)
  const int* srcA = ei;
  const int* dstA = ei + E;

  char* w = (char*)d_ws;
  auto alloc = [&](size_t bytes) {
    char* p = w;
    w += (bytes + 255) & ~(size_t)255;
    return p;
  };
  int*   deg2      = (int*)alloc((size_t)2 * N * 4);      // degd | degs
  int*   degd      = deg2;
  int*   degs      = deg2 + N;
  int*   row_start = (int*)alloc((size_t)(N + 1) * 4);
  int*   srow      = (int*)alloc((size_t)(N + 1) * 4);
  int*   cursor    = (int*)alloc((size_t)N * 4);
  int*   scursor   = (int*)alloc((size_t)N * 4);
  int*   eid       = (int*)alloc((size_t)EN * 4);
  int*   srcc      = (int*)alloc((size_t)EN * 4);
  int*   inv       = (int*)alloc((size_t)EN * 4);
  int*   smap      = (int*)alloc((size_t)EN * 4);
  float* xp        = (float*)alloc((size_t)N * THC * 4);  // 82 MB
  float* al_s      = (float*)alloc((size_t)N * TH * 4);
  float* al_d      = (float*)alloc((size_t)N * TH * 4);
  float* ale1      = (float*)alloc((size_t)E * TH * 4);   // 6.4 MB
  float* ale2      = (float*)alloc((size_t)E * TH * 4);   // 6.4 MB
  float* att       = (float*)alloc((size_t)EN * TH * 4);  // 7.7 MB
  float* z         = (float*)alloc((size_t)EN * TC * 4);  // 30.7 MB
  float* w_e       = (float*)alloc((size_t)2 * TD * TH * 4);
  const int nrb  = (N + 63) / 64;    // 313 row blocks (64 rows each)
  const int Npad = nrb * 64;         // 20032
  unsigned short* xbh = (unsigned short*)alloc((size_t)Npad * TD * 2);
  unsigned short* xbl = (unsigned short*)alloc((size_t)Npad * TD * 2);
  unsigned short* Wbh = (unsigned short*)alloc((size_t)2 * 64 * 2 * 64 * 8 * 2);
  unsigned short* Wbl = (unsigned short*)alloc((size_t)2 * 64 * 2 * 64 * 8 * 2);
  unsigned short* Webh = (unsigned short*)alloc((size_t)4 * 512 * 2);
  unsigned short* Webl = (unsigned short*)alloc((size_t)4 * 512 * 2);

  // CSR (by dst) + CSC (by src) build, shared by both layers
  hipMemsetAsync(deg2, 0, (size_t)2 * N * 4, stream);
  k_count2<<<(EN + 255) / 256, 256, 0, stream>>>(srcA, dstA, E, N, degd, degs);
  k_scan2<<<2, 1024, 0, stream>>>(degd, N, row_start, cursor, degs, srow, scursor);
  k_scatter_dst<<<(EN + 255) / 256, 256, 0, stream>>>(srcA, dstA, E, N, cursor, eid, srcc, inv);
  k_scatter_src<<<(EN + 255) / 256, 256, 0, stream>>>(srcA, E, N, scursor, inv, smap);

  // W fragment-pack + edge-attention logits for BOTH layers up-front (MFMA)
  k_prep_w<<<(2 * 64 * 2 * 64 + 255) / 256, 256, 0, stream>>>(W1, W2, Wbh, Wbl);
  k_we2<<<8, 256, 0, stream>>>(We1, ae1, We2, ae2, w_e);
  k_pack_we<<<1, 256, 0, stream>>>(w_e, Webh, Webl);
  k_al_e_mfma<<<(E + 63) / 64, 256, 0, stream>>>(ea, Webh, Webl, E, ale1, ale2);

  const int mmgrid = nrb * 8;        // 2504 blocks (64 rows x 2 heads), XCD-swizzled
  const size_t WBL = 64 * 2 * 64 * 8;  // per-layer Wb elements

  // layer 1 (k_sum_z writes the bf16 split of h directly -> no layer-2 prep)
  k_prep_x<<<(Npad * 8 + 255) / 256, 256, 0, stream>>>(x, N, Npad, xbh, xbl);
  k_matmul_mfma<<<mmgrid, 256, 0, stream>>>(xbh, xbl, Wbh, Wbl, as1, ad1,
                                            N, nrb, xp, al_s, al_d);
  k_att<<<(N + 3) / 4, 256, 0, stream>>>(al_s, al_d, ale1, row_start, eid, srcc, E, N, att);
  k_csc_z<<<(N + 3) / 4, 256, 0, stream>>>(xp, att, srow, smap, N, z);
  k_sum_z<<<(N + 15) / 16, 256, 0, stream>>>(z, row_start, b1, N, nullptr, xbh, xbl);

  // layer 2
  k_matmul_mfma<<<mmgrid, 256, 0, stream>>>(xbh, xbl, Wbh + WBL, Wbl + WBL, as2, ad2,
                                            N, nrb, xp, al_s, al_d);
  k_att<<<(N + 3) / 4, 256, 0, stream>>>(al_s, al_d, ale2, row_start, eid, srcc, E, N, att);
  k_csc_z<<<(N + 3) / 4, 256, 0, stream>>>(xp, att, srow, smap, N, z);
  k_sum_z<<<(N + 15) / 16, 256, 0, stream>>>(z, row_start, b2, N, (float*)d_out, nullptr, nullptr);
}